// Round 1
// baseline (336.290 us; speedup 1.0000x reference)
//
#include <hip/hip_runtime.h>

#define B_ 16
#define C_ 512
#define N_ 1024

typedef __attribute__((ext_vector_type(8))) short bf16x8_t;
typedef __attribute__((ext_vector_type(4))) float f32x4_t;

__device__ __forceinline__ unsigned short f2bf(float f) {
  unsigned int u = __float_as_uint(f);
  u += 0x7fffu + ((u >> 16) & 1u);
  return (unsigned short)(u >> 16);
}

__device__ __forceinline__ f32x4_t mfma16(bf16x8_t a, bf16x8_t b, f32x4_t c) {
  return __builtin_amdgcn_mfma_f32_16x16x32_bf16(a, b, c, 0, 0, 0);
}

// ---------------------------------------------------------------- weights cast
__global__ __launch_bounds__(256) void castw_k(
    const float* __restrict__ qw, const float* __restrict__ kw,
    const float* __restrict__ vw, const float* __restrict__ pw,
    unsigned short* __restrict__ Wq, unsigned short* __restrict__ Wk,
    unsigned short* __restrict__ Wv, unsigned short* __restrict__ Wp) {
  int i = blockIdx.x * 256 + threadIdx.x;  // 262144 elements each
  Wq[i] = f2bf(qw[i]);
  Wk[i] = f2bf(kw[i]);
  Wv[i] = f2bf(vw[i]);
  Wp[i] = f2bf(pw[i]);
}

// ---------------------------------------------------------------- group norm
// One WG per (b, g). Group covers channels [g*16,(g+1)*16) over all 1024 spatial
// positions = 16384 CONTIGUOUS floats in x (b,c,n). Writes hn transposed to
// (b, n, c) bf16 so it is directly the B^T operand of the conv GEMMs.
__global__ __launch_bounds__(256) void groupnorm_k(
    const float* __restrict__ x, const float* __restrict__ gw,
    const float* __restrict__ gb, unsigned short* __restrict__ hn) {
  int b = blockIdx.x >> 5, g = blockIdx.x & 31;
  int tid = threadIdx.x;
  const float* xg = x + ((long)b * C_ + g * 16) * N_;  // 16384 contiguous
  float s = 0.f, s2 = 0.f;
  for (int i = tid; i < 4096; i += 256) {
    float4 v = ((const float4*)xg)[i];
    s += v.x + v.y + v.z + v.w;
    s2 += v.x * v.x + v.y * v.y + v.z * v.z + v.w * v.w;
  }
#pragma unroll
  for (int m = 1; m < 64; m <<= 1) {
    s += __shfl_xor(s, m);
    s2 += __shfl_xor(s2, m);
  }
  __shared__ float rs[4], rs2[4];
  int wave = tid >> 6;
  if ((tid & 63) == 0) { rs[wave] = s; rs2[wave] = s2; }
  __syncthreads();
  s = rs[0] + rs[1] + rs[2] + rs[3];
  s2 = rs2[0] + rs2[1] + rs2[2] + rs2[3];
  float mean = s * (1.f / 16384.f);
  float rv = rsqrtf(s2 * (1.f / 16384.f) - mean * mean + 1e-5f);
  // normalize + transpose-write
  for (int i4 = tid; i4 < 4096; i4 += 256) {
    float4 v = ((const float4*)xg)[i4];
    int i = i4 * 4;
    int cl = i >> 10;          // channel within group (4 elems share it)
    int n0 = i & 1023;         // spatial, 4 consecutive
    int c = g * 16 + cl;
    float ga = gw[c] * rv, be = gb[c] - mean * ga;  // (x-mean)*rv*gw+gb
    unsigned short* hp = hn + ((long)b * N_ + n0) * C_ + c;
    hp[0 * C_] = f2bf(v.x * ga + be);
    hp[1 * C_] = f2bf(v.y * ga + be);
    hp[2 * C_] = f2bf(v.z * ga + be);
    hp[3 * C_] = f2bf(v.w * ga + be);
  }
}

// ---------------------------------------------------------------- GEMM (B^T)
// C[M,N] = A[M,K] * B[N,K]^T ; 128x128 tile, BK=64, 4 waves (2x2), bf16 MFMA.
// MODE 0: out bf16, (n,c) layout: out[col*ldo+row] = (acc+bias[row])*scale
// MODE 1: out bf16, (c,n) layout: out[row*ldo+col]
// MODE 2: out f32,  (c,n) layout: acc + bias[row] + resid[row*ldo+col]
template <int MODE>
__global__ __launch_bounds__(256) void gemm_bt(
    const unsigned short* __restrict__ A, int lda, long sA,
    const unsigned short* __restrict__ Bm, int ldb, long sB,
    const float* __restrict__ bias, const float* __restrict__ resid, long sR,
    void* __restrict__ outp, int ldo, long sO, int K, float scale) {
  int bz = blockIdx.z;
  const unsigned short* Ab = A + (long)bz * sA + (long)blockIdx.x * 128 * lda;
  const unsigned short* Bb = Bm + (long)bz * sB + (long)blockIdx.y * 128 * ldb;
  __shared__ char lds[32768];
  char* As = lds;
  char* Bs = lds + 16384;
  int tid = threadIdx.x;
  int lane = tid & 63, wave = tid >> 6;
  int wr = wave >> 1, wc = wave & 1;
  int lrow = lane & 15, kgrp = lane >> 4;
  f32x4_t acc[4][4];
#pragma unroll
  for (int i = 0; i < 4; ++i)
#pragma unroll
    for (int j = 0; j < 4; ++j) acc[i][j] = (f32x4_t){0.f, 0.f, 0.f, 0.f};

  int nkt = K >> 6;
  for (int kt = 0; kt < nkt; ++kt) {
    __syncthreads();
#pragma unroll
    for (int it = 0; it < 4; ++it) {  // stage 128x64 bf16 A and B tiles
      int ci = it * 256 + tid;
      int row = ci >> 3;
      int kb8 = (ci & 7) * 8;  // element offset within row
      int o = row * 128 + kb8 * 2;
      int osw = o ^ ((row & 7) << 4);  // bank-conflict XOR swizzle
      *(uint4*)(As + osw) = *(const uint4*)(Ab + (long)row * lda + kt * 64 + kb8);
      *(uint4*)(Bs + osw) = *(const uint4*)(Bb + (long)row * ldb + kt * 64 + kb8);
    }
    __syncthreads();
#pragma unroll
    for (int ks = 0; ks < 2; ++ks) {
      bf16x8_t af[4], bfv[4];
#pragma unroll
      for (int mi = 0; mi < 4; ++mi) {
        int r = wr * 64 + mi * 16 + lrow;
        int o = r * 128 + ks * 64 + kgrp * 16;
        o ^= (r & 7) << 4;
        af[mi] = *(bf16x8_t*)(As + o);
      }
#pragma unroll
      for (int ni = 0; ni < 4; ++ni) {
        int r = wc * 64 + ni * 16 + lrow;
        int o = r * 128 + ks * 64 + kgrp * 16;
        o ^= (r & 7) << 4;
        bfv[ni] = *(bf16x8_t*)(Bs + o);
      }
#pragma unroll
      for (int mi = 0; mi < 4; ++mi)
#pragma unroll
        for (int ni = 0; ni < 4; ++ni)
          acc[mi][ni] = mfma16(af[mi], bfv[ni], acc[mi][ni]);
    }
  }

  int rowbase = blockIdx.x * 128 + wr * 64;
  int colbase = blockIdx.y * 128 + wc * 64;
#pragma unroll
  for (int mi = 0; mi < 4; ++mi) {
#pragma unroll
    for (int ni = 0; ni < 4; ++ni) {
      int row0 = rowbase + mi * 16 + kgrp * 4;
      int col = colbase + ni * 16 + lrow;
      if constexpr (MODE == 0) {
        unsigned short us[4];
#pragma unroll
        for (int rg = 0; rg < 4; ++rg) {
          float v = acc[mi][ni][rg];
          if (bias) v += bias[row0 + rg];
          us[rg] = f2bf(v * scale);
        }
        unsigned short* ob = (unsigned short*)outp + (long)bz * sO;
        *(ushort4*)(ob + (long)col * ldo + row0) =
            make_ushort4(us[0], us[1], us[2], us[3]);
      } else if constexpr (MODE == 1) {
        unsigned short* ob = (unsigned short*)outp + (long)bz * sO;
#pragma unroll
        for (int rg = 0; rg < 4; ++rg) {
          float v = acc[mi][ni][rg];
          if (bias) v += bias[row0 + rg];
          ob[(long)(row0 + rg) * ldo + col] = f2bf(v * scale);
        }
      } else {
        float* ob = (float*)outp + (long)bz * sO;
        const float* rb = resid + (long)bz * sR;
#pragma unroll
        for (int rg = 0; rg < 4; ++rg) {
          int r = row0 + rg;
          ob[(long)r * ldo + col] =
              acc[mi][ni][rg] + bias[r] + rb[(long)r * ldo + col];
        }
      }
    }
  }
}

// ---------------------------------------------------------------- QK^T+softmax
// WG = (b, block of 16 query rows). 4 waves each own 256 key columns; scores
// stay in MFMA accumulators (16 frags x f32x4); softmax via 16-lane shuffle +
// tiny LDS cross-wave reduce. q is pre-scaled by 1/sqrt(C). attn out bf16 (i,j).
__global__ __launch_bounds__(256) void attn_k(
    const unsigned short* __restrict__ q, const unsigned short* __restrict__ k,
    unsigned short* __restrict__ attn) {
  int b = blockIdx.y, ib = blockIdx.x;
  int tid = threadIdx.x, lane = tid & 63, wave = tid >> 6;
  int lrow = lane & 15, kgrp = lane >> 4;
  __shared__ char qs[16384];
  __shared__ float red[2][4][16];
  const unsigned short* qb = q + ((long)b * N_ + ib * 16) * C_;  // 16KB contig
#pragma unroll
  for (int it = 0; it < 4; ++it) {
    int ci = it * 256 + tid;
    int o = ci * 16;
    int row = o >> 10;  // row stride 1024B
    int osw = o ^ ((row & 7) << 4);
    *(uint4*)(qs + osw) = *(const uint4*)((const char*)qb + o);
  }
  __syncthreads();
  f32x4_t acc[16];
#pragma unroll
  for (int t = 0; t < 16; ++t) acc[t] = (f32x4_t){0.f, 0.f, 0.f, 0.f};
  const unsigned short* kbp = k + (long)b * N_ * C_;
  int colbase = wave * 256;
  for (int ks = 0; ks < 16; ++ks) {  // K = 512, 32 per MFMA
    int kkB = ks * 64 + kgrp * 16;   // byte offset within 1024B row
    int qo = (lrow << 10) + kkB;
    qo ^= (lrow & 7) << 4;
    bf16x8_t af = *(bf16x8_t*)(qs + qo);
    const char* kbase = (const char*)kbp + (long)(colbase + lrow) * 1024 + kkB;
#pragma unroll
    for (int t = 0; t < 16; ++t) {
      bf16x8_t bfv = *(const bf16x8_t*)(kbase + (long)t * 16 * 1024);
      acc[t] = mfma16(af, bfv, acc[t]);
    }
  }
  // ---- softmax over the full row (cols split across waves) ----
  float mx[4] = {-1e30f, -1e30f, -1e30f, -1e30f};
#pragma unroll
  for (int t = 0; t < 16; ++t)
#pragma unroll
    for (int rg = 0; rg < 4; ++rg) mx[rg] = fmaxf(mx[rg], acc[t][rg]);
#pragma unroll
  for (int m = 1; m < 16; m <<= 1)
#pragma unroll
    for (int rg = 0; rg < 4; ++rg) mx[rg] = fmaxf(mx[rg], __shfl_xor(mx[rg], m));
  if (lrow == 0) {
#pragma unroll
    for (int rg = 0; rg < 4; ++rg) red[0][wave][kgrp * 4 + rg] = mx[rg];
  }
  __syncthreads();
  float gm[4], sm[4] = {0.f, 0.f, 0.f, 0.f};
#pragma unroll
  for (int rg = 0; rg < 4; ++rg) {
    int r = kgrp * 4 + rg;
    gm[rg] = fmaxf(fmaxf(red[0][0][r], red[0][1][r]),
                   fmaxf(red[0][2][r], red[0][3][r]));
  }
#pragma unroll
  for (int t = 0; t < 16; ++t)
#pragma unroll
    for (int rg = 0; rg < 4; ++rg) {
      float p = __expf(acc[t][rg] - gm[rg]);
      acc[t][rg] = p;
      sm[rg] += p;
    }
#pragma unroll
  for (int m = 1; m < 16; m <<= 1)
#pragma unroll
    for (int rg = 0; rg < 4; ++rg) sm[rg] += __shfl_xor(sm[rg], m);
  if (lrow == 0) {
#pragma unroll
    for (int rg = 0; rg < 4; ++rg) red[1][wave][kgrp * 4 + rg] = sm[rg];
  }
  __syncthreads();
  float inv[4];
#pragma unroll
  for (int rg = 0; rg < 4; ++rg) {
    int r = kgrp * 4 + rg;
    inv[rg] = 1.f / (red[1][0][r] + red[1][1][r] + red[1][2][r] + red[1][3][r]);
  }
  unsigned short* ab = attn + ((long)b * N_ + ib * 16) * N_;
#pragma unroll
  for (int t = 0; t < 16; ++t)
#pragma unroll
    for (int rg = 0; rg < 4; ++rg) {
      int r = kgrp * 4 + rg;
      int col = colbase + t * 16 + lrow;
      ab[(long)r * N_ + col] = f2bf(acc[t][rg] * inv[rg]);
    }
}

// ---------------------------------------------------------------- launch
extern "C" void kernel_launch(void* const* d_in, const int* in_sizes, int n_in,
                              void* d_out, int out_size, void* d_ws,
                              size_t ws_size, hipStream_t stream) {
  (void)in_sizes; (void)n_in; (void)out_size; (void)ws_size;
  const float* x = (const float*)d_in[0];
  const float* nw = (const float*)d_in[1];
  const float* nb = (const float*)d_in[2];
  const float* qw = (const float*)d_in[3];
  const float* qbias = (const float*)d_in[4];
  const float* kw = (const float*)d_in[5];
  const float* kbias = (const float*)d_in[6];
  const float* vw = (const float*)d_in[7];
  const float* vbias = (const float*)d_in[8];
  const float* pw = (const float*)d_in[9];
  const float* pbias = (const float*)d_in[10];
  float* out = (float*)d_out;

  char* ws = (char*)d_ws;
  unsigned short* Wq = (unsigned short*)(ws + 0);
  unsigned short* Wk = (unsigned short*)(ws + 524288);
  unsigned short* Wv = (unsigned short*)(ws + 1048576);
  unsigned short* Wp = (unsigned short*)(ws + 1572864);
  unsigned short* HN = (unsigned short*)(ws + 2097152);    // 16MB (b,n,c); reused as attnout
  unsigned short* Q = (unsigned short*)(ws + 18874368);    // 16MB (b,n,c)
  unsigned short* Kb = (unsigned short*)(ws + 35651584);   // 16MB (b,n,c)
  unsigned short* V = (unsigned short*)(ws + 52428800);    // 16MB (b,c,n)
  unsigned short* ATT = (unsigned short*)(ws + 69206016);  // 32MB (b,i,j)

  castw_k<<<1024, 256, 0, stream>>>(qw, kw, vw, pw, Wq, Wk, Wv, Wp);
  groupnorm_k<<<512, 256, 0, stream>>>(x, nw, nb, HN);

  const float scale = 0.04419417382415922f;  // 512^-0.5
  dim3 gg(4, 8, B_);
  // q = (Wq*hn + qb)*scale -> (b,n,c)
  gemm_bt<0><<<gg, 256, 0, stream>>>(Wq, 512, 0, HN, 512, (long)N_ * C_, qbias,
                                     nullptr, 0, Q, 512, (long)N_ * C_, 512, scale);
  // k -> (b,n,c)
  gemm_bt<0><<<gg, 256, 0, stream>>>(Wk, 512, 0, HN, 512, (long)N_ * C_, kbias,
                                     nullptr, 0, Kb, 512, (long)N_ * C_, 512, 1.f);
  // v -> (b,c,n)
  gemm_bt<1><<<gg, 256, 0, stream>>>(Wv, 512, 0, HN, 512, (long)N_ * C_, vbias,
                                     nullptr, 0, V, 1024, (long)C_ * N_, 512, 1.f);
  // attn = softmax(q^T k) -> (b,i,j) bf16
  attn_k<<<dim3(64, B_), 256, 0, stream>>>(Q, Kb, ATT);
  // attnout[c,i] = sum_j v[c,j] attn[i,j] -> stored (b,i,c) into HN region
  gemm_bt<0><<<gg, 256, 0, stream>>>(V, 1024, (long)C_ * N_, ATT, 1024,
                                     (long)N_ * N_, nullptr, nullptr, 0, HN, 512,
                                     (long)N_ * C_, 1024, 1.f);
  // out = x + Wp*attnout + pb  (fp32, (b,c,n))
  gemm_bt<2><<<gg, 256, 0, stream>>>(Wp, 512, 0, HN, 512, (long)N_ * C_, pbias,
                                     x, (long)C_ * N_, out, 1024, (long)C_ * N_,
                                     512, 1.f);
}

// Round 2
// 249.807 us; speedup vs baseline: 1.3462x; 1.3462x over previous
//
#include <hip/hip_runtime.h>

#define B_ 16
#define C_ 512
#define N_ 1024

typedef __attribute__((ext_vector_type(8))) short bf16x8_t;
typedef __attribute__((ext_vector_type(4))) float f32x4_t;

__device__ __forceinline__ unsigned short f2bf(float f) {
  unsigned int u = __float_as_uint(f);
  u += 0x7fffu + ((u >> 16) & 1u);
  return (unsigned short)(u >> 16);
}

__device__ __forceinline__ f32x4_t mfma16(bf16x8_t a, bf16x8_t b, f32x4_t c) {
  return __builtin_amdgcn_mfma_f32_16x16x32_bf16(a, b, c, 0, 0, 0);
}

// ---------------------------------------------------------------- weights cast
__global__ __launch_bounds__(256) void castw_k(
    const float* __restrict__ qw, const float* __restrict__ kw,
    const float* __restrict__ vw, const float* __restrict__ pw,
    unsigned short* __restrict__ Wq, unsigned short* __restrict__ Wk,
    unsigned short* __restrict__ Wv, unsigned short* __restrict__ Wp) {
  int i = blockIdx.x * 256 + threadIdx.x;  // 262144 elements each
  Wq[i] = f2bf(qw[i]);
  Wk[i] = f2bf(kw[i]);
  Wv[i] = f2bf(vw[i]);
  Wp[i] = f2bf(pw[i]);
}

// ---------------------------------------------------------------- group norm
__global__ __launch_bounds__(256) void groupnorm_k(
    const float* __restrict__ x, const float* __restrict__ gw,
    const float* __restrict__ gb, unsigned short* __restrict__ hn) {
  int b = blockIdx.x >> 5, g = blockIdx.x & 31;
  int tid = threadIdx.x;
  const float* xg = x + ((long)b * C_ + g * 16) * N_;  // 16384 contiguous
  float s = 0.f, s2 = 0.f;
  for (int i = tid; i < 4096; i += 256) {
    float4 v = ((const float4*)xg)[i];
    s += v.x + v.y + v.z + v.w;
    s2 += v.x * v.x + v.y * v.y + v.z * v.z + v.w * v.w;
  }
#pragma unroll
  for (int m = 1; m < 64; m <<= 1) {
    s += __shfl_xor(s, m);
    s2 += __shfl_xor(s2, m);
  }
  __shared__ float rs[4], rs2[4];
  int wave = tid >> 6;
  if ((tid & 63) == 0) { rs[wave] = s; rs2[wave] = s2; }
  __syncthreads();
  s = rs[0] + rs[1] + rs[2] + rs[3];
  s2 = rs2[0] + rs2[1] + rs2[2] + rs2[3];
  float mean = s * (1.f / 16384.f);
  float rv = rsqrtf(s2 * (1.f / 16384.f) - mean * mean + 1e-5f);
  for (int i4 = tid; i4 < 4096; i4 += 256) {
    float4 v = ((const float4*)xg)[i4];
    int i = i4 * 4;
    int cl = i >> 10;
    int n0 = i & 1023;
    int c = g * 16 + cl;
    float ga = gw[c] * rv, be = gb[c] - mean * ga;
    unsigned short* hp = hn + ((long)b * N_ + n0) * C_ + c;
    hp[0 * C_] = f2bf(v.x * ga + be);
    hp[1 * C_] = f2bf(v.y * ga + be);
    hp[2 * C_] = f2bf(v.z * ga + be);
    hp[3 * C_] = f2bf(v.w * ga + be);
  }
}

// ---------------------------------------------------------------- GEMM (B^T)
// C[M,N] = A[M,K] * B[N,K]^T ; 128x128 tile, BK=64, 4 waves (2x2), bf16 MFMA.
// MODE 0: out bf16, (n,c): out[col*ldo+row] = (acc+bias[row])*scale
// MODE 1: out bf16, (c,n): out[row*ldo+col]
// MODE 2: out f32,  (c,n): acc + bias[row] + resid[row*ldo+col]
// MODE 3: out bf16, fragment-blocked K2[b][n/16][c/8][n%16][c%8] (for attn B-frags)
template <int MODE>
__global__ __launch_bounds__(256) void gemm_bt(
    const unsigned short* __restrict__ A, int lda, long sA,
    const unsigned short* __restrict__ Bm, int ldb, long sB,
    const float* __restrict__ bias, const float* __restrict__ resid, long sR,
    void* __restrict__ outp, int ldo, long sO, int K, float scale) {
  int bz = blockIdx.z;
  const unsigned short* Ab = A + (long)bz * sA + (long)blockIdx.x * 128 * lda;
  const unsigned short* Bb = Bm + (long)bz * sB + (long)blockIdx.y * 128 * ldb;
  __shared__ char lds[32768];
  char* As = lds;
  char* Bs = lds + 16384;
  int tid = threadIdx.x;
  int lane = tid & 63, wave = tid >> 6;
  int wr = wave >> 1, wc = wave & 1;
  int lrow = lane & 15, kgrp = lane >> 4;
  f32x4_t acc[4][4];
#pragma unroll
  for (int i = 0; i < 4; ++i)
#pragma unroll
    for (int j = 0; j < 4; ++j) acc[i][j] = (f32x4_t){0.f, 0.f, 0.f, 0.f};

  int nkt = K >> 6;
  for (int kt = 0; kt < nkt; ++kt) {
    __syncthreads();
#pragma unroll
    for (int it = 0; it < 4; ++it) {
      int ci = it * 256 + tid;
      int row = ci >> 3;
      int kb8 = (ci & 7) * 8;
      int o = row * 128 + kb8 * 2;
      int osw = o ^ ((row & 7) << 4);
      *(uint4*)(As + osw) = *(const uint4*)(Ab + (long)row * lda + kt * 64 + kb8);
      *(uint4*)(Bs + osw) = *(const uint4*)(Bb + (long)row * ldb + kt * 64 + kb8);
    }
    __syncthreads();
#pragma unroll
    for (int ks = 0; ks < 2; ++ks) {
      bf16x8_t af[4], bfv[4];
#pragma unroll
      for (int mi = 0; mi < 4; ++mi) {
        int r = wr * 64 + mi * 16 + lrow;
        int o = r * 128 + ks * 64 + kgrp * 16;
        o ^= (r & 7) << 4;
        af[mi] = *(bf16x8_t*)(As + o);
      }
#pragma unroll
      for (int ni = 0; ni < 4; ++ni) {
        int r = wc * 64 + ni * 16 + lrow;
        int o = r * 128 + ks * 64 + kgrp * 16;
        o ^= (r & 7) << 4;
        bfv[ni] = *(bf16x8_t*)(Bs + o);
      }
#pragma unroll
      for (int mi = 0; mi < 4; ++mi)
#pragma unroll
        for (int ni = 0; ni < 4; ++ni)
          acc[mi][ni] = mfma16(af[mi], bfv[ni], acc[mi][ni]);
    }
  }

  int rowbase = blockIdx.x * 128 + wr * 64;
  int colbase = blockIdx.y * 128 + wc * 64;
#pragma unroll
  for (int mi = 0; mi < 4; ++mi) {
#pragma unroll
    for (int ni = 0; ni < 4; ++ni) {
      int row0 = rowbase + mi * 16 + kgrp * 4;
      int col = colbase + ni * 16 + lrow;
      if constexpr (MODE == 0) {
        unsigned short us[4];
#pragma unroll
        for (int rg = 0; rg < 4; ++rg) {
          float v = acc[mi][ni][rg];
          if (bias) v += bias[row0 + rg];
          us[rg] = f2bf(v * scale);
        }
        unsigned short* ob = (unsigned short*)outp + (long)bz * sO;
        *(ushort4*)(ob + (long)col * ldo + row0) =
            make_ushort4(us[0], us[1], us[2], us[3]);
      } else if constexpr (MODE == 1) {
        unsigned short* ob = (unsigned short*)outp + (long)bz * sO;
#pragma unroll
        for (int rg = 0; rg < 4; ++rg) {
          float v = acc[mi][ni][rg];
          if (bias) v += bias[row0 + rg];
          ob[(long)(row0 + rg) * ldo + col] = f2bf(v * scale);
        }
      } else if constexpr (MODE == 2) {
        float* ob = (float*)outp + (long)bz * sO;
        const float* rb = resid + (long)bz * sR;
#pragma unroll
        for (int rg = 0; rg < 4; ++rg) {
          int r = row0 + rg;
          ob[(long)r * ldo + col] =
              acc[mi][ni][rg] + bias[r] + rb[(long)r * ldo + col];
        }
      } else {  // MODE 3: fragment-blocked bf16
        unsigned short us[4];
#pragma unroll
        for (int rg = 0; rg < 4; ++rg) {
          float v = acc[mi][ni][rg];
          if (bias) v += bias[row0 + rg];
          us[rg] = f2bf(v);
        }
        unsigned short* ob = (unsigned short*)outp + ((long)bz << 19);
        long off = ((long)(col >> 4) << 13) + ((long)(row0 >> 3) << 7) +
                   ((col & 15) << 3) + (row0 & 7);
        *(ushort4*)(ob + off) = make_ushort4(us[0], us[1], us[2], us[3]);
      }
    }
  }
}

// ---------------------------------------------------------------- QK^T+softmax
// WG = (b, block of 16 query rows). 4 waves each own 256 key columns; K comes
// from the fragment-blocked K2 layout -> every fragment load is a contiguous
// 1KB wave load (16B/lane). Scores stay in MFMA accumulators; softmax via
// 16-lane shuffle + tiny LDS cross-wave reduce. q pre-scaled by 1/sqrt(C).
__global__ __launch_bounds__(256) void attn_k(
    const unsigned short* __restrict__ q, const unsigned short* __restrict__ k2,
    unsigned short* __restrict__ attn) {
  int b = blockIdx.y, ib = blockIdx.x;
  int tid = threadIdx.x, lane = tid & 63, wave = tid >> 6;
  int lrow = lane & 15, kgrp = lane >> 4;
  __shared__ char qs[16384];
  __shared__ float red[2][4][16];
  const unsigned short* qb = q + ((long)b * N_ + ib * 16) * C_;  // 16KB contig
#pragma unroll
  for (int it = 0; it < 4; ++it) {
    int ci = it * 256 + tid;
    int o = ci * 16;
    int row = o >> 10;
    int osw = o ^ ((row & 7) << 4);
    *(uint4*)(qs + osw) = *(const uint4*)((const char*)qb + o);
  }
  __syncthreads();
  f32x4_t acc[16];
#pragma unroll
  for (int t = 0; t < 16; ++t) acc[t] = (f32x4_t){0.f, 0.f, 0.f, 0.f};
  int colbase = wave * 256;
  // K2[b][nt][kk][16][8]: per nt block = 16KB; fragment (ks,kgrp,lrow) is
  // contiguous: addr = base + nt*8192 + ks*512 + lane*8 (elements).
  const unsigned short* kb2 =
      k2 + ((long)b << 19) + ((long)(colbase >> 4) << 13) + lane * 8;
  for (int ks = 0; ks < 16; ++ks) {  // K = 512, 32 per MFMA
    int kkB = ks * 64 + kgrp * 16;
    int qo = (lrow << 10) + kkB;
    qo ^= (lrow & 7) << 4;
    bf16x8_t af = *(bf16x8_t*)(qs + qo);
    const unsigned short* kp = kb2 + ks * 512;
    bf16x8_t kf[16];
#pragma unroll
    for (int t = 0; t < 16; ++t) kf[t] = *(const bf16x8_t*)(kp + t * 8192);
#pragma unroll
    for (int t = 0; t < 16; ++t) acc[t] = mfma16(af, kf[t], acc[t]);
  }
  // ---- softmax over the full row (cols split across waves) ----
  float mx[4] = {-1e30f, -1e30f, -1e30f, -1e30f};
#pragma unroll
  for (int t = 0; t < 16; ++t)
#pragma unroll
    for (int rg = 0; rg < 4; ++rg) mx[rg] = fmaxf(mx[rg], acc[t][rg]);
#pragma unroll
  for (int m = 1; m < 16; m <<= 1)
#pragma unroll
    for (int rg = 0; rg < 4; ++rg) mx[rg] = fmaxf(mx[rg], __shfl_xor(mx[rg], m));
  if (lrow == 0) {
#pragma unroll
    for (int rg = 0; rg < 4; ++rg) red[0][wave][kgrp * 4 + rg] = mx[rg];
  }
  __syncthreads();
  float gm[4], sm[4] = {0.f, 0.f, 0.f, 0.f};
#pragma unroll
  for (int rg = 0; rg < 4; ++rg) {
    int r = kgrp * 4 + rg;
    gm[rg] = fmaxf(fmaxf(red[0][0][r], red[0][1][r]),
                   fmaxf(red[0][2][r], red[0][3][r]));
  }
#pragma unroll
  for (int t = 0; t < 16; ++t)
#pragma unroll
    for (int rg = 0; rg < 4; ++rg) {
      float p = __expf(acc[t][rg] - gm[rg]);
      acc[t][rg] = p;
      sm[rg] += p;
    }
#pragma unroll
  for (int m = 1; m < 16; m <<= 1)
#pragma unroll
    for (int rg = 0; rg < 4; ++rg) sm[rg] += __shfl_xor(sm[rg], m);
  if (lrow == 0) {
#pragma unroll
    for (int rg = 0; rg < 4; ++rg) red[1][wave][kgrp * 4 + rg] = sm[rg];
  }
  __syncthreads();
  float inv[4];
#pragma unroll
  for (int rg = 0; rg < 4; ++rg) {
    int r = kgrp * 4 + rg;
    inv[rg] = 1.f / (red[1][0][r] + red[1][1][r] + red[1][2][r] + red[1][3][r]);
  }
  unsigned short* ab = attn + ((long)b * N_ + ib * 16) * N_;
#pragma unroll
  for (int t = 0; t < 16; ++t)
#pragma unroll
    for (int rg = 0; rg < 4; ++rg) {
      int r = kgrp * 4 + rg;
      int col = colbase + t * 16 + lrow;
      ab[(long)r * N_ + col] = f2bf(acc[t][rg] * inv[rg]);
    }
}

// ---------------------------------------------------------------- launch
extern "C" void kernel_launch(void* const* d_in, const int* in_sizes, int n_in,
                              void* d_out, int out_size, void* d_ws,
                              size_t ws_size, hipStream_t stream) {
  (void)in_sizes; (void)n_in; (void)out_size; (void)ws_size;
  const float* x = (const float*)d_in[0];
  const float* nw = (const float*)d_in[1];
  const float* nb = (const float*)d_in[2];
  const float* qw = (const float*)d_in[3];
  const float* qbias = (const float*)d_in[4];
  const float* kw = (const float*)d_in[5];
  const float* kbias = (const float*)d_in[6];
  const float* vw = (const float*)d_in[7];
  const float* vbias = (const float*)d_in[8];
  const float* pw = (const float*)d_in[9];
  const float* pbias = (const float*)d_in[10];
  float* out = (float*)d_out;

  char* ws = (char*)d_ws;
  unsigned short* Wq = (unsigned short*)(ws + 0);
  unsigned short* Wk = (unsigned short*)(ws + 524288);
  unsigned short* Wv = (unsigned short*)(ws + 1048576);
  unsigned short* Wp = (unsigned short*)(ws + 1572864);
  unsigned short* HN = (unsigned short*)(ws + 2097152);    // 16MB (b,n,c); reused as attnout
  unsigned short* Q = (unsigned short*)(ws + 18874368);    // 16MB (b,n,c)
  unsigned short* K2 = (unsigned short*)(ws + 35651584);   // 16MB frag-blocked
  unsigned short* V = (unsigned short*)(ws + 52428800);    // 16MB (b,c,n)
  unsigned short* ATT = (unsigned short*)(ws + 69206016);  // 32MB (b,i,j)

  castw_k<<<1024, 256, 0, stream>>>(qw, kw, vw, pw, Wq, Wk, Wv, Wp);
  groupnorm_k<<<512, 256, 0, stream>>>(x, nw, nb, HN);

  const float scale = 0.04419417382415922f;  // 512^-0.5
  dim3 gg(4, 8, B_);
  // q = (Wq*hn + qb)*scale -> (b,n,c)
  gemm_bt<0><<<gg, 256, 0, stream>>>(Wq, 512, 0, HN, 512, (long)N_ * C_, qbias,
                                     nullptr, 0, Q, 512, (long)N_ * C_, 512, scale);
  // k -> fragment-blocked K2
  gemm_bt<3><<<gg, 256, 0, stream>>>(Wk, 512, 0, HN, 512, (long)N_ * C_, kbias,
                                     nullptr, 0, K2, 0, 0, 512, 1.f);
  // v -> (b,c,n)
  gemm_bt<1><<<gg, 256, 0, stream>>>(Wv, 512, 0, HN, 512, (long)N_ * C_, vbias,
                                     nullptr, 0, V, 1024, (long)C_ * N_, 512, 1.f);
  // attn = softmax(q^T k) -> (b,i,j) bf16
  attn_k<<<dim3(64, B_), 256, 0, stream>>>(Q, K2, ATT);
  // attnout[c,i] = sum_j v[c,j] attn[i,j] -> stored (b,i,c) into HN region
  gemm_bt<0><<<gg, 256, 0, stream>>>(V, 1024, (long)C_ * N_, ATT, 1024,
                                     (long)N_ * N_, nullptr, nullptr, 0, HN, 512,
                                     (long)N_ * C_, 1024, 1.f);
  // out = x + Wp*attnout + pb  (fp32, (b,c,n))
  gemm_bt<2><<<gg, 256, 0, stream>>>(Wp, 512, 0, HN, 512, (long)N_ * C_, pbias,
                                     x, (long)C_ * N_, out, 1024, (long)C_ * N_,
                                     512, 1.f);
}

// Round 3
// 249.413 us; speedup vs baseline: 1.3483x; 1.0016x over previous
//
#include <hip/hip_runtime.h>

#define B_ 16
#define C_ 512
#define N_ 1024

typedef __attribute__((ext_vector_type(8))) short bf16x8_t;
typedef __attribute__((ext_vector_type(4))) float f32x4_t;

__device__ __forceinline__ unsigned short f2bf(float f) {
  unsigned int u = __float_as_uint(f);
  u += 0x7fffu + ((u >> 16) & 1u);
  return (unsigned short)(u >> 16);
}

__device__ __forceinline__ f32x4_t mfma16(bf16x8_t a, bf16x8_t b, f32x4_t c) {
  return __builtin_amdgcn_mfma_f32_16x16x32_bf16(a, b, c, 0, 0, 0);
}

// ---------------------------------------------------------------- weights cast
__global__ __launch_bounds__(256) void castw_k(
    const float* __restrict__ qw, const float* __restrict__ kw,
    const float* __restrict__ vw, const float* __restrict__ pw,
    unsigned short* __restrict__ Wq, unsigned short* __restrict__ Wk,
    unsigned short* __restrict__ Wv, unsigned short* __restrict__ Wp) {
  int i = blockIdx.x * 256 + threadIdx.x;  // 262144 elements each
  Wq[i] = f2bf(qw[i]);
  Wk[i] = f2bf(kw[i]);
  Wv[i] = f2bf(vw[i]);
  Wp[i] = f2bf(pw[i]);
}

// ---------------------------------------------------------------- group norm
__global__ __launch_bounds__(256) void groupnorm_k(
    const float* __restrict__ x, const float* __restrict__ gw,
    const float* __restrict__ gb, unsigned short* __restrict__ hn) {
  int b = blockIdx.x >> 5, g = blockIdx.x & 31;
  int tid = threadIdx.x;
  const float* xg = x + ((long)b * C_ + g * 16) * N_;  // 16384 contiguous
  float s = 0.f, s2 = 0.f;
  for (int i = tid; i < 4096; i += 256) {
    float4 v = ((const float4*)xg)[i];
    s += v.x + v.y + v.z + v.w;
    s2 += v.x * v.x + v.y * v.y + v.z * v.z + v.w * v.w;
  }
#pragma unroll
  for (int m = 1; m < 64; m <<= 1) {
    s += __shfl_xor(s, m);
    s2 += __shfl_xor(s2, m);
  }
  __shared__ float rs[4], rs2[4];
  int wave = tid >> 6;
  if ((tid & 63) == 0) { rs[wave] = s; rs2[wave] = s2; }
  __syncthreads();
  s = rs[0] + rs[1] + rs[2] + rs[3];
  s2 = rs2[0] + rs2[1] + rs2[2] + rs2[3];
  float mean = s * (1.f / 16384.f);
  float rv = rsqrtf(s2 * (1.f / 16384.f) - mean * mean + 1e-5f);
  for (int i4 = tid; i4 < 4096; i4 += 256) {
    float4 v = ((const float4*)xg)[i4];
    int i = i4 * 4;
    int cl = i >> 10;
    int n0 = i & 1023;
    int c = g * 16 + cl;
    float ga = gw[c] * rv, be = gb[c] - mean * ga;
    unsigned short* hp = hn + ((long)b * N_ + n0) * C_ + c;
    hp[0 * C_] = f2bf(v.x * ga + be);
    hp[1 * C_] = f2bf(v.y * ga + be);
    hp[2 * C_] = f2bf(v.z * ga + be);
    hp[3 * C_] = f2bf(v.w * ga + be);
  }
}

// ---------------------------------------------------------------- GEMM (B^T)
// C[M,N] = A[M,K] * B[N,K]^T ; 128x128 tile, BK=64, 4 waves (2x2), bf16 MFMA.
// MODE 0: out bf16, (n,c): out[col*ldo+row] = (acc+bias[row])*scale
// MODE 1: out bf16, (c,n): out[row*ldo+col]
// MODE 2: out f32,  (c,n): acc + bias[row] + resid[row*ldo+col]
// MODE 3: out bf16, fragment-blocked K2[b][n/16][c/8][n%16][c%8] (for attn B-frags)
template <int MODE>
__global__ __launch_bounds__(256) void gemm_bt(
    const unsigned short* __restrict__ A, int lda, long sA,
    const unsigned short* __restrict__ Bm, int ldb, long sB,
    const float* __restrict__ bias, const float* __restrict__ resid, long sR,
    void* __restrict__ outp, int ldo, long sO, int K, float scale) {
  int bz = blockIdx.z;
  const unsigned short* Ab = A + (long)bz * sA + (long)blockIdx.x * 128 * lda;
  const unsigned short* Bb = Bm + (long)bz * sB + (long)blockIdx.y * 128 * ldb;
  __shared__ char lds[32768];
  char* As = lds;
  char* Bs = lds + 16384;
  int tid = threadIdx.x;
  int lane = tid & 63, wave = tid >> 6;
  int wr = wave >> 1, wc = wave & 1;
  int lrow = lane & 15, kgrp = lane >> 4;
  f32x4_t acc[4][4];
#pragma unroll
  for (int i = 0; i < 4; ++i)
#pragma unroll
    for (int j = 0; j < 4; ++j) acc[i][j] = (f32x4_t){0.f, 0.f, 0.f, 0.f};

  int nkt = K >> 6;
  for (int kt = 0; kt < nkt; ++kt) {
    __syncthreads();
#pragma unroll
    for (int it = 0; it < 4; ++it) {
      int ci = it * 256 + tid;
      int row = ci >> 3;
      int kb8 = (ci & 7) * 8;
      int o = row * 128 + kb8 * 2;
      int osw = o ^ ((row & 7) << 4);
      *(uint4*)(As + osw) = *(const uint4*)(Ab + (long)row * lda + kt * 64 + kb8);
      *(uint4*)(Bs + osw) = *(const uint4*)(Bb + (long)row * ldb + kt * 64 + kb8);
    }
    __syncthreads();
#pragma unroll
    for (int ks = 0; ks < 2; ++ks) {
      bf16x8_t af[4], bfv[4];
#pragma unroll
      for (int mi = 0; mi < 4; ++mi) {
        int r = wr * 64 + mi * 16 + lrow;
        int o = r * 128 + ks * 64 + kgrp * 16;
        o ^= (r & 7) << 4;
        af[mi] = *(bf16x8_t*)(As + o);
      }
#pragma unroll
      for (int ni = 0; ni < 4; ++ni) {
        int r = wc * 64 + ni * 16 + lrow;
        int o = r * 128 + ks * 64 + kgrp * 16;
        o ^= (r & 7) << 4;
        bfv[ni] = *(bf16x8_t*)(Bs + o);
      }
#pragma unroll
      for (int mi = 0; mi < 4; ++mi)
#pragma unroll
        for (int ni = 0; ni < 4; ++ni)
          acc[mi][ni] = mfma16(af[mi], bfv[ni], acc[mi][ni]);
    }
  }

  int rowbase = blockIdx.x * 128 + wr * 64;
  int colbase = blockIdx.y * 128 + wc * 64;
#pragma unroll
  for (int mi = 0; mi < 4; ++mi) {
#pragma unroll
    for (int ni = 0; ni < 4; ++ni) {
      int row0 = rowbase + mi * 16 + kgrp * 4;
      int col = colbase + ni * 16 + lrow;
      if constexpr (MODE == 0) {
        unsigned short us[4];
#pragma unroll
        for (int rg = 0; rg < 4; ++rg) {
          float v = acc[mi][ni][rg];
          if (bias) v += bias[row0 + rg];
          us[rg] = f2bf(v * scale);
        }
        unsigned short* ob = (unsigned short*)outp + (long)bz * sO;
        *(ushort4*)(ob + (long)col * ldo + row0) =
            make_ushort4(us[0], us[1], us[2], us[3]);
      } else if constexpr (MODE == 1) {
        unsigned short* ob = (unsigned short*)outp + (long)bz * sO;
#pragma unroll
        for (int rg = 0; rg < 4; ++rg) {
          float v = acc[mi][ni][rg];
          if (bias) v += bias[row0 + rg];
          ob[(long)(row0 + rg) * ldo + col] = f2bf(v * scale);
        }
      } else if constexpr (MODE == 2) {
        float* ob = (float*)outp + (long)bz * sO;
        const float* rb = resid + (long)bz * sR;
#pragma unroll
        for (int rg = 0; rg < 4; ++rg) {
          int r = row0 + rg;
          ob[(long)r * ldo + col] =
              acc[mi][ni][rg] + bias[r] + rb[(long)r * ldo + col];
        }
      } else {  // MODE 3: fragment-blocked bf16
        unsigned short us[4];
#pragma unroll
        for (int rg = 0; rg < 4; ++rg) {
          float v = acc[mi][ni][rg];
          if (bias) v += bias[row0 + rg];
          us[rg] = f2bf(v);
        }
        unsigned short* ob = (unsigned short*)outp + ((long)bz << 19);
        long off = ((long)(col >> 4) << 13) + ((long)(row0 >> 3) << 7) +
                   ((col & 15) << 3) + (row0 & 7);
        *(ushort4*)(ob + off) = make_ushort4(us[0], us[1], us[2], us[3]);
      }
    }
  }
}

// ---------------------------------------------------------------- QK^T+softmax
// WG = (b, block of 16 query rows). 4 waves each own 256 key columns; K comes
// from the fragment-blocked K2 layout -> every fragment load is a contiguous
// 1KB wave load (16B/lane). Scores stay in MFMA accumulators; softmax via
// 16-lane shuffle + tiny LDS cross-wave reduce. q pre-scaled by 1/sqrt(C).
__global__ __launch_bounds__(256) void attn_k(
    const unsigned short* __restrict__ q, const unsigned short* __restrict__ k2,
    unsigned short* __restrict__ attn) {
  int b = blockIdx.y, ib = blockIdx.x;
  int tid = threadIdx.x, lane = tid & 63, wave = tid >> 6;
  int lrow = lane & 15, kgrp = lane >> 4;
  __shared__ char qs[16384];
  __shared__ float red[2][4][16];
  const unsigned short* qb = q + ((long)b * N_ + ib * 16) * C_;  // 16KB contig
#pragma unroll
  for (int it = 0; it < 4; ++it) {
    int ci = it * 256 + tid;
    int o = ci * 16;
    int row = o >> 10;
    int osw = o ^ ((row & 7) << 4);
    *(uint4*)(qs + osw) = *(const uint4*)((const char*)qb + o);
  }
  __syncthreads();
  f32x4_t acc[16];
#pragma unroll
  for (int t = 0; t < 16; ++t) acc[t] = (f32x4_t){0.f, 0.f, 0.f, 0.f};
  int colbase = wave * 256;
  // K2[b][nt][kk][16][8]: per nt block = 16KB; fragment (ks,kgrp,lrow) is
  // contiguous: addr = base + nt*8192 + ks*512 + lane*8 (elements).
  const unsigned short* kb2 =
      k2 + ((long)b << 19) + ((long)(colbase >> 4) << 13) + lane * 8;
  for (int ks = 0; ks < 16; ++ks) {  // K = 512, 32 per MFMA
    int kkB = ks * 64 + kgrp * 16;
    int qo = (lrow << 10) + kkB;
    qo ^= (lrow & 7) << 4;
    bf16x8_t af = *(bf16x8_t*)(qs + qo);
    const unsigned short* kp = kb2 + ks * 512;
    bf16x8_t kf[16];
#pragma unroll
    for (int t = 0; t < 16; ++t) kf[t] = *(const bf16x8_t*)(kp + t * 8192);
#pragma unroll
    for (int t = 0; t < 16; ++t) acc[t] = mfma16(af, kf[t], acc[t]);
  }
  // ---- softmax over the full row (cols split across waves) ----
  float mx[4] = {-1e30f, -1e30f, -1e30f, -1e30f};
#pragma unroll
  for (int t = 0; t < 16; ++t)
#pragma unroll
    for (int rg = 0; rg < 4; ++rg) mx[rg] = fmaxf(mx[rg], acc[t][rg]);
#pragma unroll
  for (int m = 1; m < 16; m <<= 1)
#pragma unroll
    for (int rg = 0; rg < 4; ++rg) mx[rg] = fmaxf(mx[rg], __shfl_xor(mx[rg], m));
  if (lrow == 0) {
#pragma unroll
    for (int rg = 0; rg < 4; ++rg) red[0][wave][kgrp * 4 + rg] = mx[rg];
  }
  __syncthreads();
  float gm[4], sm[4] = {0.f, 0.f, 0.f, 0.f};
#pragma unroll
  for (int rg = 0; rg < 4; ++rg) {
    int r = kgrp * 4 + rg;
    gm[rg] = fmaxf(fmaxf(red[0][0][r], red[0][1][r]),
                   fmaxf(red[0][2][r], red[0][3][r]));
  }
#pragma unroll
  for (int t = 0; t < 16; ++t)
#pragma unroll
    for (int rg = 0; rg < 4; ++rg) {
      float p = __expf(acc[t][rg] - gm[rg]);
      acc[t][rg] = p;
      sm[rg] += p;
    }
#pragma unroll
  for (int m = 1; m < 16; m <<= 1)
#pragma unroll
    for (int rg = 0; rg < 4; ++rg) sm[rg] += __shfl_xor(sm[rg], m);
  if (lrow == 0) {
#pragma unroll
    for (int rg = 0; rg < 4; ++rg) red[1][wave][kgrp * 4 + rg] = sm[rg];
  }
  __syncthreads();
  float inv[4];
#pragma unroll
  for (int rg = 0; rg < 4; ++rg) {
    int r = kgrp * 4 + rg;
    inv[rg] = 1.f / (red[1][0][r] + red[1][1][r] + red[1][2][r] + red[1][3][r]);
  }
  unsigned short* ab = attn + ((long)b * N_ + ib * 16) * N_;
#pragma unroll
  for (int t = 0; t < 16; ++t)
#pragma unroll
    for (int rg = 0; rg < 4; ++rg) {
      int r = kgrp * 4 + rg;
      int col = colbase + t * 16 + lrow;
      ab[(long)r * N_ + col] = f2bf(acc[t][rg] * inv[rg]);
    }
}

// ---------------------------------------------------------------- launch
extern "C" void kernel_launch(void* const* d_in, const int* in_sizes, int n_in,
                              void* d_out, int out_size, void* d_ws,
                              size_t ws_size, hipStream_t stream) {
  (void)in_sizes; (void)n_in; (void)out_size; (void)ws_size;
  const float* x = (const float*)d_in[0];
  const float* nw = (const float*)d_in[1];
  const float* nb = (const float*)d_in[2];
  const float* qw = (const float*)d_in[3];
  const float* qbias = (const float*)d_in[4];
  const float* kw = (const float*)d_in[5];
  const float* kbias = (const float*)d_in[6];
  const float* vw = (const float*)d_in[7];
  const float* vbias = (const float*)d_in[8];
  const float* pw = (const float*)d_in[9];
  const float* pbias = (const float*)d_in[10];
  float* out = (float*)d_out;

  char* ws = (char*)d_ws;
  unsigned short* Wq = (unsigned short*)(ws + 0);
  unsigned short* Wk = (unsigned short*)(ws + 524288);
  unsigned short* Wv = (unsigned short*)(ws + 1048576);
  unsigned short* Wp = (unsigned short*)(ws + 1572864);
  unsigned short* HN = (unsigned short*)(ws + 2097152);    // 16MB (b,n,c); reused as attnout
  unsigned short* Q = (unsigned short*)(ws + 18874368);    // 16MB (b,n,c)
  unsigned short* K2 = (unsigned short*)(ws + 35651584);   // 16MB frag-blocked
  unsigned short* V = (unsigned short*)(ws + 52428800);    // 16MB (b,c,n)
  unsigned short* ATT = (unsigned short*)(ws + 69206016);  // 32MB (b,i,j)

  castw_k<<<1024, 256, 0, stream>>>(qw, kw, vw, pw, Wq, Wk, Wv, Wp);
  groupnorm_k<<<512, 256, 0, stream>>>(x, nw, nb, HN);

  const float scale = 0.04419417382415922f;  // 512^-0.5
  dim3 gg(4, 8, B_);
  // q = (Wq*hn + qb)*scale -> (b,n,c)
  gemm_bt<0><<<gg, 256, 0, stream>>>(Wq, 512, 0, HN, 512, (long)N_ * C_, qbias,
                                     nullptr, 0, Q, 512, (long)N_ * C_, 512, scale);
  // k -> fragment-blocked K2
  gemm_bt<3><<<gg, 256, 0, stream>>>(Wk, 512, 0, HN, 512, (long)N_ * C_, kbias,
                                     nullptr, 0, K2, 0, 0, 512, 1.f);
  // v -> (b,c,n)
  gemm_bt<1><<<gg, 256, 0, stream>>>(Wv, 512, 0, HN, 512, (long)N_ * C_, vbias,
                                     nullptr, 0, V, 1024, (long)C_ * N_, 512, 1.f);
  // attn = softmax(q^T k) -> (b,i,j) bf16
  attn_k<<<dim3(64, B_), 256, 0, stream>>>(Q, K2, ATT);
  // attnout[c,i] = sum_j v[c,j] attn[i,j] -> stored (b,i,c) into HN region
  gemm_bt<0><<<gg, 256, 0, stream>>>(V, 1024, (long)C_ * N_, ATT, 1024,
                                     (long)N_ * N_, nullptr, nullptr, 0, HN, 512,
                                     (long)N_ * C_, 1024, 1.f);
  // out = x + Wp*attnout + pb  (fp32, (b,c,n))
  gemm_bt<2><<<gg, 256, 0, stream>>>(Wp, 512, 0, HN, 512, (long)N_ * C_, pbias,
                                     x, (long)C_ * N_, out, 1024, (long)C_ * N_,
                                     512, 1.f);
}

// Round 4
// 203.863 us; speedup vs baseline: 1.6496x; 1.2234x over previous
//
#include <hip/hip_runtime.h>

#define B_ 16
#define C_ 512
#define N_ 1024

typedef __attribute__((ext_vector_type(8))) short bf16x8_t;
typedef __attribute__((ext_vector_type(4))) float f32x4_t;

__device__ __forceinline__ unsigned short f2bf(float f) {
  unsigned int u = __float_as_uint(f);
  u += 0x7fffu + ((u >> 16) & 1u);
  return (unsigned short)(u >> 16);
}

__device__ __forceinline__ f32x4_t mfma16(bf16x8_t a, bf16x8_t b, f32x4_t c) {
  return __builtin_amdgcn_mfma_f32_16x16x32_bf16(a, b, c, 0, 0, 0);
}

// ---------------------------------------------------------------- weights cast
__global__ __launch_bounds__(256) void castw_k(
    const float* __restrict__ qw, const float* __restrict__ kw,
    const float* __restrict__ vw, const float* __restrict__ pw,
    unsigned short* __restrict__ Wq, unsigned short* __restrict__ Wk,
    unsigned short* __restrict__ Wv, unsigned short* __restrict__ Wp) {
  int i = blockIdx.x * 256 + threadIdx.x;  // 262144 elements each
  Wq[i] = f2bf(qw[i]);
  Wk[i] = f2bf(kw[i]);
  Wv[i] = f2bf(vw[i]);
  Wp[i] = f2bf(pw[i]);
}

// ---------------------------------------------------------------- GN stats
// One block per (b, g); group slab = 16ch x 1024 = 16384 contiguous floats.
// Writes (mean, rsqrt(var+eps)) per group.
__global__ __launch_bounds__(256) void gnstats_k(
    const float* __restrict__ x, float2* __restrict__ mv) {
  int b = blockIdx.x >> 5, g = blockIdx.x & 31;
  int t = threadIdx.x;
  const float* xg = x + ((long)b * C_ + g * 16) * N_;
  float s = 0.f, s2 = 0.f;
  for (int i = t; i < 4096; i += 256) {
    float4 v = ((const float4*)xg)[i];
    s += v.x + v.y + v.z + v.w;
    s2 += v.x * v.x + v.y * v.y + v.z * v.z + v.w * v.w;
  }
#pragma unroll
  for (int m = 1; m < 64; m <<= 1) {
    s += __shfl_xor(s, m);
    s2 += __shfl_xor(s2, m);
  }
  __shared__ float rs[4], rs2[4];
  int wave = t >> 6;
  if ((t & 63) == 0) { rs[wave] = s; rs2[wave] = s2; }
  __syncthreads();
  if (t == 0) {
    s = rs[0] + rs[1] + rs[2] + rs[3];
    s2 = rs2[0] + rs2[1] + rs2[2] + rs2[3];
    float mean = s * (1.f / 16384.f);
    float rv = rsqrtf(s2 * (1.f / 16384.f) - mean * mean + 1e-5f);
    mv[b * 32 + g] = make_float2(mean, rv);
  }
}

// ---------------------------------------------------------------- GN normalize
// Block = (b, gp, nc): channels [gp*32, gp*32+32), spatial [nc*256, nc*256+256).
// Lane quad (tid&3) owns 8 channels; 4 lanes jointly write one FULL 64B line
// hn[(b,n)][gp*32..+32] -> no partial-line RMW (fixes 8x write amplification).
__global__ __launch_bounds__(256) void gnnorm_k(
    const float* __restrict__ x, const float* __restrict__ gw,
    const float* __restrict__ gb, const float2* __restrict__ mv,
    unsigned short* __restrict__ hn) {
  int f = blockIdx.x;
  int b = f >> 6, gp = (f >> 2) & 15, nc = f & 3;
  int t = threadIdx.x;
  int quad = t & 3, nrow = t >> 2;
  int h2 = quad >> 1;  // which of the two groups in this 32-ch slab
  float2 m = mv[b * 32 + gp * 2 + h2];
  int c0 = quad * 8;
  float ga[8], be[8];
#pragma unroll
  for (int jj = 0; jj < 8; ++jj) {
    int gc = gp * 32 + c0 + jj;
    ga[jj] = gw[gc] * m.y;
    be[jj] = gb[gc] - m.x * ga[jj];
  }
  const float* xg = x + ((long)b * C_ + gp * 32) * N_;
  unsigned short* ob = hn + (long)b * N_ * C_ + gp * 32 + c0;
  for (int j = 0; j < 4; ++j) {
    int n = nc * 256 + j * 64 + nrow;
    unsigned short us[8];
#pragma unroll
    for (int jj = 0; jj < 8; ++jj)
      us[jj] = f2bf(xg[(long)(c0 + jj) * N_ + n] * ga[jj] + be[jj]);
    *(uint4*)(ob + (long)n * C_) = *(uint4*)us;
  }
}

// ---------------------------------------------------------------- GEMM (B^T)
// C[M,N] = A[M,K] * B[N,K]^T ; 128x128 tile, BK=64, 4 waves (2x2), bf16 MFMA.
// MODE 0: out bf16, (n,c): out[col*ldo+row] = (acc+bias[row])*scale
// MODE 1: out bf16, (c,n): out[row*ldo+col]
// MODE 2: out f32,  (c,n): acc + bias[row] + resid[row*ldo+col]
// MODE 3: out bf16, fragment-blocked K2[b][n/16][c/8][n%16][c%8] (for attn B-frags)
template <int MODE>
__global__ __launch_bounds__(256) void gemm_bt(
    const unsigned short* __restrict__ A, int lda, long sA,
    const unsigned short* __restrict__ Bm, int ldb, long sB,
    const float* __restrict__ bias, const float* __restrict__ resid, long sR,
    void* __restrict__ outp, int ldo, long sO, int K, float scale) {
  int bz = blockIdx.z;
  const unsigned short* Ab = A + (long)bz * sA + (long)blockIdx.x * 128 * lda;
  const unsigned short* Bb = Bm + (long)bz * sB + (long)blockIdx.y * 128 * ldb;
  __shared__ char lds[32768];
  char* As = lds;
  char* Bs = lds + 16384;
  int tid = threadIdx.x;
  int lane = tid & 63, wave = tid >> 6;
  int wr = wave >> 1, wc = wave & 1;
  int lrow = lane & 15, kgrp = lane >> 4;
  f32x4_t acc[4][4];
#pragma unroll
  for (int i = 0; i < 4; ++i)
#pragma unroll
    for (int j = 0; j < 4; ++j) acc[i][j] = (f32x4_t){0.f, 0.f, 0.f, 0.f};

  int nkt = K >> 6;
  for (int kt = 0; kt < nkt; ++kt) {
    __syncthreads();
#pragma unroll
    for (int it = 0; it < 4; ++it) {
      int ci = it * 256 + tid;
      int row = ci >> 3;
      int kb8 = (ci & 7) * 8;
      int o = row * 128 + kb8 * 2;
      int osw = o ^ ((row & 7) << 4);
      *(uint4*)(As + osw) = *(const uint4*)(Ab + (long)row * lda + kt * 64 + kb8);
      *(uint4*)(Bs + osw) = *(const uint4*)(Bb + (long)row * ldb + kt * 64 + kb8);
    }
    __syncthreads();
#pragma unroll
    for (int ks = 0; ks < 2; ++ks) {
      bf16x8_t af[4], bfv[4];
#pragma unroll
      for (int mi = 0; mi < 4; ++mi) {
        int r = wr * 64 + mi * 16 + lrow;
        int o = r * 128 + ks * 64 + kgrp * 16;
        o ^= (r & 7) << 4;
        af[mi] = *(bf16x8_t*)(As + o);
      }
#pragma unroll
      for (int ni = 0; ni < 4; ++ni) {
        int r = wc * 64 + ni * 16 + lrow;
        int o = r * 128 + ks * 64 + kgrp * 16;
        o ^= (r & 7) << 4;
        bfv[ni] = *(bf16x8_t*)(Bs + o);
      }
#pragma unroll
      for (int mi = 0; mi < 4; ++mi)
#pragma unroll
        for (int ni = 0; ni < 4; ++ni)
          acc[mi][ni] = mfma16(af[mi], bfv[ni], acc[mi][ni]);
    }
  }

  int rowbase = blockIdx.x * 128 + wr * 64;
  int colbase = blockIdx.y * 128 + wc * 64;
#pragma unroll
  for (int mi = 0; mi < 4; ++mi) {
#pragma unroll
    for (int ni = 0; ni < 4; ++ni) {
      int row0 = rowbase + mi * 16 + kgrp * 4;
      int col = colbase + ni * 16 + lrow;
      if constexpr (MODE == 0) {
        unsigned short us[4];
#pragma unroll
        for (int rg = 0; rg < 4; ++rg) {
          float v = acc[mi][ni][rg];
          if (bias) v += bias[row0 + rg];
          us[rg] = f2bf(v * scale);
        }
        unsigned short* ob = (unsigned short*)outp + (long)bz * sO;
        *(ushort4*)(ob + (long)col * ldo + row0) =
            make_ushort4(us[0], us[1], us[2], us[3]);
      } else if constexpr (MODE == 1) {
        unsigned short* ob = (unsigned short*)outp + (long)bz * sO;
#pragma unroll
        for (int rg = 0; rg < 4; ++rg) {
          float v = acc[mi][ni][rg];
          if (bias) v += bias[row0 + rg];
          ob[(long)(row0 + rg) * ldo + col] = f2bf(v * scale);
        }
      } else if constexpr (MODE == 2) {
        float* ob = (float*)outp + (long)bz * sO;
        const float* rb = resid + (long)bz * sR;
#pragma unroll
        for (int rg = 0; rg < 4; ++rg) {
          int r = row0 + rg;
          ob[(long)r * ldo + col] =
              acc[mi][ni][rg] + bias[r] + rb[(long)r * ldo + col];
        }
      } else {  // MODE 3: fragment-blocked bf16
        unsigned short us[4];
#pragma unroll
        for (int rg = 0; rg < 4; ++rg) {
          float v = acc[mi][ni][rg];
          if (bias) v += bias[row0 + rg];
          us[rg] = f2bf(v);
        }
        unsigned short* ob = (unsigned short*)outp + ((long)bz << 19);
        long off = ((long)(col >> 4) << 13) + ((long)(row0 >> 3) << 7) +
                   ((col & 15) << 3) + (row0 & 7);
        *(ushort4*)(ob + off) = make_ushort4(us[0], us[1], us[2], us[3]);
      }
    }
  }
}

// ---------------------------------------------------------------- QK^T+softmax
// Flat 1024-block grid; b = f & 15 so XCD(f%8) == b%8: all 64 blocks of a batch
// share one XCD whose L2 holds that batch's K2 (1MB) -> L2-hit fragment loads.
__global__ __launch_bounds__(256) void attn_k(
    const unsigned short* __restrict__ q, const unsigned short* __restrict__ k2,
    unsigned short* __restrict__ attn) {
  int f = blockIdx.x;
  int b = f & 15, ib = f >> 4;
  int tid = threadIdx.x, lane = tid & 63, wave = tid >> 6;
  int lrow = lane & 15, kgrp = lane >> 4;
  __shared__ char qs[16384];
  __shared__ float red[2][4][16];
  const unsigned short* qb = q + ((long)b * N_ + ib * 16) * C_;  // 16KB contig
#pragma unroll
  for (int it = 0; it < 4; ++it) {
    int ci = it * 256 + tid;
    int o = ci * 16;
    int row = o >> 10;
    int osw = o ^ ((row & 7) << 4);
    *(uint4*)(qs + osw) = *(const uint4*)((const char*)qb + o);
  }
  __syncthreads();
  f32x4_t acc[16];
#pragma unroll
  for (int t = 0; t < 16; ++t) acc[t] = (f32x4_t){0.f, 0.f, 0.f, 0.f};
  int colbase = wave * 256;
  // K2[b][nt][kk][16][8]: fragment (ks,kgrp,lrow) contiguous 1KB per wave.
  const unsigned short* kb2 =
      k2 + ((long)b << 19) + ((long)(colbase >> 4) << 13) + lane * 8;
  for (int ks = 0; ks < 16; ++ks) {  // K = 512, 32 per MFMA
    int kkB = ks * 64 + kgrp * 16;
    int qo = (lrow << 10) + kkB;
    qo ^= (lrow & 7) << 4;
    bf16x8_t af = *(bf16x8_t*)(qs + qo);
    const unsigned short* kp = kb2 + ks * 512;
    bf16x8_t kf[16];
#pragma unroll
    for (int t = 0; t < 16; ++t) kf[t] = *(const bf16x8_t*)(kp + t * 8192);
#pragma unroll
    for (int t = 0; t < 16; ++t) acc[t] = mfma16(af, kf[t], acc[t]);
  }
  // ---- softmax over the full row (cols split across waves) ----
  float mx[4] = {-1e30f, -1e30f, -1e30f, -1e30f};
#pragma unroll
  for (int t = 0; t < 16; ++t)
#pragma unroll
    for (int rg = 0; rg < 4; ++rg) mx[rg] = fmaxf(mx[rg], acc[t][rg]);
#pragma unroll
  for (int m = 1; m < 16; m <<= 1)
#pragma unroll
    for (int rg = 0; rg < 4; ++rg) mx[rg] = fmaxf(mx[rg], __shfl_xor(mx[rg], m));
  if (lrow == 0) {
#pragma unroll
    for (int rg = 0; rg < 4; ++rg) red[0][wave][kgrp * 4 + rg] = mx[rg];
  }
  __syncthreads();
  float gm[4], sm[4] = {0.f, 0.f, 0.f, 0.f};
#pragma unroll
  for (int rg = 0; rg < 4; ++rg) {
    int r = kgrp * 4 + rg;
    gm[rg] = fmaxf(fmaxf(red[0][0][r], red[0][1][r]),
                   fmaxf(red[0][2][r], red[0][3][r]));
  }
#pragma unroll
  for (int t = 0; t < 16; ++t)
#pragma unroll
    for (int rg = 0; rg < 4; ++rg) {
      float p = __expf(acc[t][rg] - gm[rg]);
      acc[t][rg] = p;
      sm[rg] += p;
    }
#pragma unroll
  for (int m = 1; m < 16; m <<= 1)
#pragma unroll
    for (int rg = 0; rg < 4; ++rg) sm[rg] += __shfl_xor(sm[rg], m);
  if (lrow == 0) {
#pragma unroll
    for (int rg = 0; rg < 4; ++rg) red[1][wave][kgrp * 4 + rg] = sm[rg];
  }
  __syncthreads();
  float inv[4];
#pragma unroll
  for (int rg = 0; rg < 4; ++rg) {
    int r = kgrp * 4 + rg;
    inv[rg] = 1.f / (red[1][0][r] + red[1][1][r] + red[1][2][r] + red[1][3][r]);
  }
  unsigned short* ab = attn + ((long)b * N_ + ib * 16) * N_;
#pragma unroll
  for (int t = 0; t < 16; ++t)
#pragma unroll
    for (int rg = 0; rg < 4; ++rg) {
      int r = kgrp * 4 + rg;
      int col = colbase + t * 16 + lrow;
      ab[(long)r * N_ + col] = f2bf(acc[t][rg] * inv[rg]);
    }
}

// ---------------------------------------------------------------- launch
extern "C" void kernel_launch(void* const* d_in, const int* in_sizes, int n_in,
                              void* d_out, int out_size, void* d_ws,
                              size_t ws_size, hipStream_t stream) {
  (void)in_sizes; (void)n_in; (void)out_size; (void)ws_size;
  const float* x = (const float*)d_in[0];
  const float* nw = (const float*)d_in[1];
  const float* nb = (const float*)d_in[2];
  const float* qw = (const float*)d_in[3];
  const float* qbias = (const float*)d_in[4];
  const float* kw = (const float*)d_in[5];
  const float* kbias = (const float*)d_in[6];
  const float* vw = (const float*)d_in[7];
  const float* vbias = (const float*)d_in[8];
  const float* pw = (const float*)d_in[9];
  const float* pbias = (const float*)d_in[10];
  float* out = (float*)d_out;

  char* ws = (char*)d_ws;
  unsigned short* Wq = (unsigned short*)(ws + 0);
  unsigned short* Wk = (unsigned short*)(ws + 524288);
  unsigned short* Wv = (unsigned short*)(ws + 1048576);
  unsigned short* Wp = (unsigned short*)(ws + 1572864);
  unsigned short* HN = (unsigned short*)(ws + 2097152);    // 16MB (b,n,c); reused as attnout
  unsigned short* Q = (unsigned short*)(ws + 18874368);    // 16MB (b,n,c)
  unsigned short* K2 = (unsigned short*)(ws + 35651584);   // 16MB frag-blocked
  unsigned short* V = (unsigned short*)(ws + 52428800);    // 16MB (b,c,n)
  unsigned short* ATT = (unsigned short*)(ws + 69206016);  // 32MB (b,i,j)
  float2* MV = (float2*)(ws + 102760448);                  // 4KB (b,g) stats

  castw_k<<<1024, 256, 0, stream>>>(qw, kw, vw, pw, Wq, Wk, Wv, Wp);
  gnstats_k<<<512, 256, 0, stream>>>(x, MV);
  gnnorm_k<<<1024, 256, 0, stream>>>(x, nw, nb, MV, HN);

  const float scale = 0.04419417382415922f;  // 512^-0.5
  dim3 gg(4, 8, B_);
  // q = (Wq*hn + qb)*scale -> (b,n,c)
  gemm_bt<0><<<gg, 256, 0, stream>>>(Wq, 512, 0, HN, 512, (long)N_ * C_, qbias,
                                     nullptr, 0, Q, 512, (long)N_ * C_, 512, scale);
  // k -> fragment-blocked K2
  gemm_bt<3><<<gg, 256, 0, stream>>>(Wk, 512, 0, HN, 512, (long)N_ * C_, kbias,
                                     nullptr, 0, K2, 0, 0, 512, 1.f);
  // v -> (b,c,n)
  gemm_bt<1><<<gg, 256, 0, stream>>>(Wv, 512, 0, HN, 512, (long)N_ * C_, vbias,
                                     nullptr, 0, V, 1024, (long)C_ * N_, 512, 1.f);
  // attn = softmax(q^T k) -> (b,i,j) bf16
  attn_k<<<1024, 256, 0, stream>>>(Q, K2, ATT);
  // attnout[c,i] = sum_j v[c,j] attn[i,j] -> stored (b,i,c) into HN region
  gemm_bt<0><<<gg, 256, 0, stream>>>(V, 1024, (long)C_ * N_, ATT, 1024,
                                     (long)N_ * N_, nullptr, nullptr, 0, HN, 512,
                                     (long)N_ * C_, 1024, 1.f);
  // out = x + Wp*attnout + pb  (fp32, (b,c,n))
  gemm_bt<2><<<gg, 256, 0, stream>>>(Wp, 512, 0, HN, 512, (long)N_ * C_, pbias,
                                     x, (long)C_ * N_, out, 1024, (long)C_ * N_,
                                     512, 1.f);
}

// Round 5
// 174.061 us; speedup vs baseline: 1.9320x; 1.1712x over previous
//
#include <hip/hip_runtime.h>

#define B_ 16
#define C_ 512
#define N_ 1024

typedef __attribute__((ext_vector_type(8))) short bf16x8_t;
typedef __attribute__((ext_vector_type(4))) float f32x4_t;

__device__ __forceinline__ unsigned short f2bf(float f) {
  unsigned int u = __float_as_uint(f);
  u += 0x7fffu + ((u >> 16) & 1u);
  return (unsigned short)(u >> 16);
}

__device__ __forceinline__ f32x4_t mfma16(bf16x8_t a, bf16x8_t b, f32x4_t c) {
  return __builtin_amdgcn_mfma_f32_16x16x32_bf16(a, b, c, 0, 0, 0);
}

// async global->LDS, 16B per lane; dest must be wave-uniform base (lane*16 added by HW)
__device__ __forceinline__ void gload_lds16(const void* g, void* l) {
  __builtin_amdgcn_global_load_lds(
      (const __attribute__((address_space(1))) unsigned int*)g,
      (__attribute__((address_space(3))) unsigned int*)l, 16, 0, 0);
}

// ---------------------------------------------------------------- weights cast
__global__ __launch_bounds__(256) void castw_k(
    const float* __restrict__ qw, const float* __restrict__ kw,
    const float* __restrict__ vw, const float* __restrict__ pw,
    unsigned short* __restrict__ Wq, unsigned short* __restrict__ Wk,
    unsigned short* __restrict__ Wv, unsigned short* __restrict__ Wp) {
  int i = blockIdx.x * 256 + threadIdx.x;  // 262144 elements each
  Wq[i] = f2bf(qw[i]);
  Wk[i] = f2bf(kw[i]);
  Wv[i] = f2bf(vw[i]);
  Wp[i] = f2bf(pw[i]);
}

// ---------------------------------------------------------------- GN stats
__global__ __launch_bounds__(256) void gnstats_k(
    const float* __restrict__ x, float2* __restrict__ mv) {
  int b = blockIdx.x >> 5, g = blockIdx.x & 31;
  int t = threadIdx.x;
  const float* xg = x + ((long)b * C_ + g * 16) * N_;
  float s = 0.f, s2 = 0.f;
  for (int i = t; i < 4096; i += 256) {
    float4 v = ((const float4*)xg)[i];
    s += v.x + v.y + v.z + v.w;
    s2 += v.x * v.x + v.y * v.y + v.z * v.z + v.w * v.w;
  }
#pragma unroll
  for (int m = 1; m < 64; m <<= 1) {
    s += __shfl_xor(s, m);
    s2 += __shfl_xor(s2, m);
  }
  __shared__ float rs[4], rs2[4];
  int wave = t >> 6;
  if ((t & 63) == 0) { rs[wave] = s; rs2[wave] = s2; }
  __syncthreads();
  if (t == 0) {
    s = rs[0] + rs[1] + rs[2] + rs[3];
    s2 = rs2[0] + rs2[1] + rs2[2] + rs2[3];
    float mean = s * (1.f / 16384.f);
    float rv = rsqrtf(s2 * (1.f / 16384.f) - mean * mean + 1e-5f);
    mv[b * 32 + g] = make_float2(mean, rv);
  }
}

// ---------------------------------------------------------------- GN normalize
// Full-64B-line transposed stores (no partial-line RMW).
__global__ __launch_bounds__(256) void gnnorm_k(
    const float* __restrict__ x, const float* __restrict__ gw,
    const float* __restrict__ gb, const float2* __restrict__ mv,
    unsigned short* __restrict__ hn) {
  int f = blockIdx.x;
  int b = f >> 6, gp = (f >> 2) & 15, nc = f & 3;
  int t = threadIdx.x;
  int quad = t & 3, nrow = t >> 2;
  int h2 = quad >> 1;
  float2 m = mv[b * 32 + gp * 2 + h2];
  int c0 = quad * 8;
  float ga[8], be[8];
#pragma unroll
  for (int jj = 0; jj < 8; ++jj) {
    int gc = gp * 32 + c0 + jj;
    ga[jj] = gw[gc] * m.y;
    be[jj] = gb[gc] - m.x * ga[jj];
  }
  const float* xg = x + ((long)b * C_ + gp * 32) * N_;
  unsigned short* ob = hn + (long)b * N_ * C_ + gp * 32 + c0;
  for (int j = 0; j < 4; ++j) {
    int n = nc * 256 + j * 64 + nrow;
    unsigned short us[8];
#pragma unroll
    for (int jj = 0; jj < 8; ++jj)
      us[jj] = f2bf(xg[(long)(c0 + jj) * N_ + n] * ga[jj] + be[jj]);
    *(uint4*)(ob + (long)n * C_) = *(uint4*)us;
  }
}

// ---------------------------------------------------------------- GEMM (B^T)
// C[M,N] = A[M,K] * B[N,K]^T ; 128x128 tile, BK=64, 4 waves (2x2), bf16 MFMA.
// Staging via global_load_lds (16B/lane); LDS linear, XOR swizzle applied by
// permuting the per-lane GLOBAL source chunk (same 128B segment -> coalesced).
// MODE 0: out bf16, (n,c): out[col*ldo+row] = (acc+bias[row])*scale
// MODE 1: out bf16, (c,n): out[row*ldo+col]
// MODE 2: out f32,  (c,n): acc + bias[row] + resid[row*ldo+col]
// MODE 3: out bf16, frag-blocked [b][n/16][c/8][n%16][c%8], value*(scale)
template <int MODE>
__global__ __launch_bounds__(256) void gemm_bt(
    const unsigned short* __restrict__ A, int lda, long sA,
    const unsigned short* __restrict__ Bm, int ldb, long sB,
    const float* __restrict__ bias, const float* __restrict__ resid, long sR,
    void* __restrict__ outp, int ldo, long sO, int K, float scale) {
  int bz = blockIdx.z;
  const unsigned short* Ab = A + (long)bz * sA + (long)blockIdx.x * 128 * lda;
  const unsigned short* Bb = Bm + (long)bz * sB + (long)blockIdx.y * 128 * ldb;
  __shared__ char lds[32768];
  char* As = lds;
  char* Bs = lds + 16384;
  int tid = threadIdx.x;
  int lane = tid & 63, wave = tid >> 6;
  int wr = wave >> 1, wc = wave & 1;
  int lrow = lane & 15, kgrp = lane >> 4;
  f32x4_t acc[4][4];
#pragma unroll
  for (int i = 0; i < 4; ++i)
#pragma unroll
    for (int j = 0; j < 4; ++j) acc[i][j] = (f32x4_t){0.f, 0.f, 0.f, 0.f};

  // staging geometry: wave stages rows [wave*32, wave*32+32), 8 rows per instr;
  // lane covers row +(lane>>3), chunk (lane&7). Source chunk pre-permuted by
  // ^(row&7) == ^(lane>>3) so the swizzled read side works on linear LDS.
  int perm = (((lane & 7) ^ (lane >> 3)) << 3);
  const unsigned short* Asrc = Ab + (long)(wave * 32 + (lane >> 3)) * lda + perm;
  const unsigned short* Bsrc = Bb + (long)(wave * 32 + (lane >> 3)) * ldb + perm;
  char* Adst = As + wave * 32 * 128;
  char* Bdst = Bs + wave * 32 * 128;

  int nkt = K >> 6;
  for (int kt = 0; kt < nkt; ++kt) {
    __syncthreads();
#pragma unroll
    for (int i = 0; i < 4; ++i) {
      gload_lds16(Asrc + (long)i * 8 * lda + kt * 64, Adst + i * 1024);
      gload_lds16(Bsrc + (long)i * 8 * ldb + kt * 64, Bdst + i * 1024);
    }
    __syncthreads();
#pragma unroll
    for (int ks = 0; ks < 2; ++ks) {
      bf16x8_t af[4], bfv[4];
#pragma unroll
      for (int mi = 0; mi < 4; ++mi) {
        int r = wr * 64 + mi * 16 + lrow;
        int o = r * 128 + ks * 64 + kgrp * 16;
        o ^= (r & 7) << 4;
        af[mi] = *(bf16x8_t*)(As + o);
      }
#pragma unroll
      for (int ni = 0; ni < 4; ++ni) {
        int r = wc * 64 + ni * 16 + lrow;
        int o = r * 128 + ks * 64 + kgrp * 16;
        o ^= (r & 7) << 4;
        bfv[ni] = *(bf16x8_t*)(Bs + o);
      }
#pragma unroll
      for (int mi = 0; mi < 4; ++mi)
#pragma unroll
        for (int ni = 0; ni < 4; ++ni)
          acc[mi][ni] = mfma16(af[mi], bfv[ni], acc[mi][ni]);
    }
  }

  int rowbase = blockIdx.x * 128 + wr * 64;
  int colbase = blockIdx.y * 128 + wc * 64;
#pragma unroll
  for (int mi = 0; mi < 4; ++mi) {
#pragma unroll
    for (int ni = 0; ni < 4; ++ni) {
      int row0 = rowbase + mi * 16 + kgrp * 4;
      int col = colbase + ni * 16 + lrow;
      if constexpr (MODE == 0) {
        unsigned short us[4];
#pragma unroll
        for (int rg = 0; rg < 4; ++rg) {
          float v = acc[mi][ni][rg];
          if (bias) v += bias[row0 + rg];
          us[rg] = f2bf(v * scale);
        }
        unsigned short* ob = (unsigned short*)outp + (long)bz * sO;
        *(ushort4*)(ob + (long)col * ldo + row0) =
            make_ushort4(us[0], us[1], us[2], us[3]);
      } else if constexpr (MODE == 1) {
        unsigned short* ob = (unsigned short*)outp + (long)bz * sO;
#pragma unroll
        for (int rg = 0; rg < 4; ++rg) {
          float v = acc[mi][ni][rg];
          if (bias) v += bias[row0 + rg];
          ob[(long)(row0 + rg) * ldo + col] = f2bf(v * scale);
        }
      } else if constexpr (MODE == 2) {
        float* ob = (float*)outp + (long)bz * sO;
        const float* rb = resid + (long)bz * sR;
#pragma unroll
        for (int rg = 0; rg < 4; ++rg) {
          int r = row0 + rg;
          ob[(long)r * ldo + col] =
              acc[mi][ni][rg] + bias[r] + rb[(long)r * ldo + col];
        }
      } else {  // MODE 3: fragment-blocked bf16 (with scale)
        unsigned short us[4];
#pragma unroll
        for (int rg = 0; rg < 4; ++rg) {
          float v = acc[mi][ni][rg];
          if (bias) v += bias[row0 + rg];
          us[rg] = f2bf(v * scale);
        }
        unsigned short* ob = (unsigned short*)outp + ((long)bz << 19);
        long off = ((long)(col >> 4) << 13) + ((long)(row0 >> 3) << 7) +
                   ((col & 15) << 3) + (row0 & 7);
        *(ushort4*)(ob + off) = make_ushort4(us[0], us[1], us[2], us[3]);
      }
    }
  }
}

// ---------------------------------------------------------------- QK^T+softmax
// 512 blocks, 32 q-rows each (b = f&15 pins batch to XCD b%8; 2 blocks/CU).
// Both Q and K come frag-blocked (contiguous 1KB wave loads). Each wave owns
// 256 key cols x all 32 rows; acc = 32 f32x4 = 128 VGPR. No staging LDS.
__global__ __launch_bounds__(256, 2) void attn_k(
    const unsigned short* __restrict__ q2, const unsigned short* __restrict__ k2,
    unsigned short* __restrict__ attn) {
  int f = blockIdx.x;
  int b = f & 15, ib = f >> 4;  // ib 0..31 -> rows ib*32..+32
  int tid = threadIdx.x, lane = tid & 63, wave = tid >> 6;
  int lrow = lane & 15, kgrp = lane >> 4;
  __shared__ float red[2][4][32];
  f32x4_t acc[2][16];
#pragma unroll
  for (int h = 0; h < 2; ++h)
#pragma unroll
    for (int t = 0; t < 16; ++t) acc[h][t] = (f32x4_t){0.f, 0.f, 0.f, 0.f};
  const unsigned short* qb =
      q2 + ((long)b << 19) + ((long)(ib * 2) << 13) + lane * 8;
  const unsigned short* kb =
      k2 + ((long)b << 19) + ((long)(wave * 16) << 13) + lane * 8;
  for (int ks = 0; ks < 16; ++ks) {  // K = 512
    bf16x8_t qa[2];
    qa[0] = *(const bf16x8_t*)(qb + ks * 512);
    qa[1] = *(const bf16x8_t*)(qb + 8192 + ks * 512);
    bf16x8_t kf[16];
#pragma unroll
    for (int t = 0; t < 16; ++t)
      kf[t] = *(const bf16x8_t*)(kb + t * 8192 + ks * 512);
#pragma unroll
    for (int t = 0; t < 16; ++t) {
      acc[0][t] = mfma16(qa[0], kf[t], acc[0][t]);
      acc[1][t] = mfma16(qa[1], kf[t], acc[1][t]);
    }
  }
  // ---- softmax: rows r = h*16 + kgrp*4 + rg; cols split across waves ----
  float mx[2][4] = {{-1e30f, -1e30f, -1e30f, -1e30f},
                    {-1e30f, -1e30f, -1e30f, -1e30f}};
#pragma unroll
  for (int h = 0; h < 2; ++h)
#pragma unroll
    for (int t = 0; t < 16; ++t)
#pragma unroll
      for (int rg = 0; rg < 4; ++rg) mx[h][rg] = fmaxf(mx[h][rg], acc[h][t][rg]);
#pragma unroll
  for (int m = 1; m < 16; m <<= 1)
#pragma unroll
    for (int h = 0; h < 2; ++h)
#pragma unroll
      for (int rg = 0; rg < 4; ++rg)
        mx[h][rg] = fmaxf(mx[h][rg], __shfl_xor(mx[h][rg], m));
  if (lrow == 0) {
#pragma unroll
    for (int h = 0; h < 2; ++h)
#pragma unroll
      for (int rg = 0; rg < 4; ++rg)
        red[0][wave][h * 16 + kgrp * 4 + rg] = mx[h][rg];
  }
  __syncthreads();
  float gm[2][4], sm[2][4] = {{0.f, 0.f, 0.f, 0.f}, {0.f, 0.f, 0.f, 0.f}};
#pragma unroll
  for (int h = 0; h < 2; ++h)
#pragma unroll
    for (int rg = 0; rg < 4; ++rg) {
      int r = h * 16 + kgrp * 4 + rg;
      gm[h][rg] = fmaxf(fmaxf(red[0][0][r], red[0][1][r]),
                        fmaxf(red[0][2][r], red[0][3][r]));
    }
#pragma unroll
  for (int h = 0; h < 2; ++h)
#pragma unroll
    for (int t = 0; t < 16; ++t)
#pragma unroll
      for (int rg = 0; rg < 4; ++rg) {
        float p = __expf(acc[h][t][rg] - gm[h][rg]);
        acc[h][t][rg] = p;
        sm[h][rg] += p;
      }
#pragma unroll
  for (int m = 1; m < 16; m <<= 1)
#pragma unroll
    for (int h = 0; h < 2; ++h)
#pragma unroll
      for (int rg = 0; rg < 4; ++rg) sm[h][rg] += __shfl_xor(sm[h][rg], m);
  if (lrow == 0) {
#pragma unroll
    for (int h = 0; h < 2; ++h)
#pragma unroll
      for (int rg = 0; rg < 4; ++rg)
        red[1][wave][h * 16 + kgrp * 4 + rg] = sm[h][rg];
  }
  __syncthreads();
  unsigned short* ab = attn + ((long)b * N_ + ib * 32) * N_;
#pragma unroll
  for (int h = 0; h < 2; ++h)
#pragma unroll
    for (int rg = 0; rg < 4; ++rg) {
      int r = h * 16 + kgrp * 4 + rg;
      float inv =
          1.f / (red[1][0][r] + red[1][1][r] + red[1][2][r] + red[1][3][r]);
#pragma unroll
      for (int t = 0; t < 16; ++t) {
        int col = wave * 256 + t * 16 + lrow;
        ab[(long)r * N_ + col] = f2bf(acc[h][t][rg] * inv);
      }
    }
}

// ---------------------------------------------------------------- launch
extern "C" void kernel_launch(void* const* d_in, const int* in_sizes, int n_in,
                              void* d_out, int out_size, void* d_ws,
                              size_t ws_size, hipStream_t stream) {
  (void)in_sizes; (void)n_in; (void)out_size; (void)ws_size;
  const float* x = (const float*)d_in[0];
  const float* nw = (const float*)d_in[1];
  const float* nb = (const float*)d_in[2];
  const float* qw = (const float*)d_in[3];
  const float* qbias = (const float*)d_in[4];
  const float* kw = (const float*)d_in[5];
  const float* kbias = (const float*)d_in[6];
  const float* vw = (const float*)d_in[7];
  const float* vbias = (const float*)d_in[8];
  const float* pw = (const float*)d_in[9];
  const float* pbias = (const float*)d_in[10];
  float* out = (float*)d_out;

  char* ws = (char*)d_ws;
  unsigned short* Wq = (unsigned short*)(ws + 0);
  unsigned short* Wk = (unsigned short*)(ws + 524288);
  unsigned short* Wv = (unsigned short*)(ws + 1048576);
  unsigned short* Wp = (unsigned short*)(ws + 1572864);
  unsigned short* HN = (unsigned short*)(ws + 2097152);    // 16MB (b,n,c); reused as attnout
  unsigned short* Q2 = (unsigned short*)(ws + 18874368);   // 16MB frag-blocked
  unsigned short* K2 = (unsigned short*)(ws + 35651584);   // 16MB frag-blocked
  unsigned short* V = (unsigned short*)(ws + 52428800);    // 16MB (b,c,n)
  unsigned short* ATT = (unsigned short*)(ws + 69206016);  // 32MB (b,i,j)
  float2* MV = (float2*)(ws + 102760448);                  // 4KB (b,g) stats

  castw_k<<<1024, 256, 0, stream>>>(qw, kw, vw, pw, Wq, Wk, Wv, Wp);
  gnstats_k<<<512, 256, 0, stream>>>(x, MV);
  gnnorm_k<<<1024, 256, 0, stream>>>(x, nw, nb, MV, HN);

  const float scale = 0.04419417382415922f;  // 512^-0.5
  dim3 gg(4, 8, B_);
  // q -> frag-blocked Q2, scaled
  gemm_bt<3><<<gg, 256, 0, stream>>>(Wq, 512, 0, HN, 512, (long)N_ * C_, qbias,
                                     nullptr, 0, Q2, 0, 0, 512, scale);
  // k -> frag-blocked K2
  gemm_bt<3><<<gg, 256, 0, stream>>>(Wk, 512, 0, HN, 512, (long)N_ * C_, kbias,
                                     nullptr, 0, K2, 0, 0, 512, 1.f);
  // v -> (b,c,n)
  gemm_bt<1><<<gg, 256, 0, stream>>>(Wv, 512, 0, HN, 512, (long)N_ * C_, vbias,
                                     nullptr, 0, V, 1024, (long)C_ * N_, 512, 1.f);
  // attn = softmax(q^T k) -> (b,i,j) bf16
  attn_k<<<512, 256, 0, stream>>>(Q2, K2, ATT);
  // attnout[c,i] = sum_j v[c,j] attn[i,j] -> stored (b,i,c) into HN region
  gemm_bt<0><<<gg, 256, 0, stream>>>(V, 1024, (long)C_ * N_, ATT, 1024,
                                     (long)N_ * N_, nullptr, nullptr, 0, HN, 512,
                                     (long)N_ * C_, 1024, 1.f);
  // out = x + Wp*attnout + pb  (fp32, (b,c,n))
  gemm_bt<2><<<gg, 256, 0, stream>>>(Wp, 512, 0, HN, 512, (long)N_ * C_, pbias,
                                     x, (long)C_ * N_, out, 1024, (long)C_ * N_,
                                     512, 1.f);
}

// Round 6
// 145.163 us; speedup vs baseline: 2.3166x; 1.1991x over previous
//
#include <hip/hip_runtime.h>

#define B_ 16
#define C_ 512
#define N_ 1024

typedef __attribute__((ext_vector_type(8))) short bf16x8_t;
typedef __attribute__((ext_vector_type(4))) float f32x4_t;

__device__ __forceinline__ unsigned short f2bf(float f) {
  unsigned int u = __float_as_uint(f);
  u += 0x7fffu + ((u >> 16) & 1u);
  return (unsigned short)(u >> 16);
}

__device__ __forceinline__ f32x4_t mfma16(bf16x8_t a, bf16x8_t b, f32x4_t c) {
  return __builtin_amdgcn_mfma_f32_16x16x32_bf16(a, b, c, 0, 0, 0);
}

// async global->LDS, 16B per lane; dest must be wave-uniform base (lane*16 added by HW)
__device__ __forceinline__ void gload_lds16(const void* g, void* l) {
  __builtin_amdgcn_global_load_lds(
      (const __attribute__((address_space(1))) unsigned int*)g,
      (__attribute__((address_space(3))) unsigned int*)l, 16, 0, 0);
}

// ---------------------------------------------------------------- weights cast
// Stacks Wq|Wk|Wv into one (1536x512) bf16 buffer for the fused qkv GEMM.
__global__ __launch_bounds__(256) void castw_k(
    const float* __restrict__ qw, const float* __restrict__ kw,
    const float* __restrict__ vw, const float* __restrict__ pw,
    unsigned short* __restrict__ Wqkv, unsigned short* __restrict__ Wp) {
  int i = blockIdx.x * 256 + threadIdx.x;  // 262144 elements each
  Wqkv[i] = f2bf(qw[i]);
  Wqkv[262144 + i] = f2bf(kw[i]);
  Wqkv[524288 + i] = f2bf(vw[i]);
  Wp[i] = f2bf(pw[i]);
}

// ---------------------------------------------------------------- GN stats
__global__ __launch_bounds__(256) void gnstats_k(
    const float* __restrict__ x, float2* __restrict__ mv) {
  int b = blockIdx.x >> 5, g = blockIdx.x & 31;
  int t = threadIdx.x;
  const float* xg = x + ((long)b * C_ + g * 16) * N_;
  float s = 0.f, s2 = 0.f;
  for (int i = t; i < 4096; i += 256) {
    float4 v = ((const float4*)xg)[i];
    s += v.x + v.y + v.z + v.w;
    s2 += v.x * v.x + v.y * v.y + v.z * v.z + v.w * v.w;
  }
#pragma unroll
  for (int m = 1; m < 64; m <<= 1) {
    s += __shfl_xor(s, m);
    s2 += __shfl_xor(s2, m);
  }
  __shared__ float rs[4], rs2[4];
  int wave = t >> 6;
  if ((t & 63) == 0) { rs[wave] = s; rs2[wave] = s2; }
  __syncthreads();
  if (t == 0) {
    s = rs[0] + rs[1] + rs[2] + rs[3];
    s2 = rs2[0] + rs2[1] + rs2[2] + rs2[3];
    float mean = s * (1.f / 16384.f);
    float rv = rsqrtf(s2 * (1.f / 16384.f) - mean * mean + 1e-5f);
    mv[b * 32 + g] = make_float2(mean, rv);
  }
}

// ---------------------------------------------------------------- GN normalize
// Full-64B-line transposed stores (no partial-line RMW).
__global__ __launch_bounds__(256) void gnnorm_k(
    const float* __restrict__ x, const float* __restrict__ gw,
    const float* __restrict__ gb, const float2* __restrict__ mv,
    unsigned short* __restrict__ hn) {
  int f = blockIdx.x;
  int b = f >> 6, gp = (f >> 2) & 15, nc = f & 3;
  int t = threadIdx.x;
  int quad = t & 3, nrow = t >> 2;
  int h2 = quad >> 1;
  float2 m = mv[b * 32 + gp * 2 + h2];
  int c0 = quad * 8;
  float ga[8], be[8];
#pragma unroll
  for (int jj = 0; jj < 8; ++jj) {
    int gc = gp * 32 + c0 + jj;
    ga[jj] = gw[gc] * m.y;
    be[jj] = gb[gc] - m.x * ga[jj];
  }
  const float* xg = x + ((long)b * C_ + gp * 32) * N_;
  unsigned short* ob = hn + (long)b * N_ * C_ + gp * 32 + c0;
  for (int j = 0; j < 4; ++j) {
    int n = nc * 256 + j * 64 + nrow;
    unsigned short us[8];
#pragma unroll
    for (int jj = 0; jj < 8; ++jj)
      us[jj] = f2bf(xg[(long)(c0 + jj) * N_ + n] * ga[jj] + be[jj]);
    *(uint4*)(ob + (long)n * C_) = *(uint4*)us;
  }
}

// ---------------------------------------------------------------- QKV GEMM
// A = stacked Wqkv (1536x512), B = HN (b,n,c). 128x128 tile, BK=64, gload_lds
// staging with source-side XOR permute. Epilogue per 512-row slab:
//  slab 0 -> Q2 frag-blocked [n/16][c/8][n%16][c%8], *scale
//  slab 1 -> K2 same layout
//  slab 2 -> V2 frag-blocked [c/16][n/8][c%16][n%8] (transposed roles for PV)
__global__ __launch_bounds__(256) void gemm_qkv(
    const unsigned short* __restrict__ W, const unsigned short* __restrict__ HN,
    const float* __restrict__ qb, const float* __restrict__ kb,
    const float* __restrict__ vb, unsigned short* __restrict__ Q2,
    unsigned short* __restrict__ K2, unsigned short* __restrict__ V2,
    float scale) {
  int bz = blockIdx.z;
  const unsigned short* Ab = W + (long)blockIdx.x * 128 * 512;
  const unsigned short* Bb =
      HN + (long)bz * N_ * C_ + (long)blockIdx.y * 128 * 512;
  __shared__ char lds[32768];
  char* As = lds;
  char* Bs = lds + 16384;
  int tid = threadIdx.x;
  int lane = tid & 63, wave = tid >> 6;
  int wr = wave >> 1, wc = wave & 1;
  int lrow = lane & 15, kgrp = lane >> 4;
  f32x4_t acc[4][4];
#pragma unroll
  for (int i = 0; i < 4; ++i)
#pragma unroll
    for (int j = 0; j < 4; ++j) acc[i][j] = (f32x4_t){0.f, 0.f, 0.f, 0.f};

  int perm = (((lane & 7) ^ (lane >> 3)) << 3);
  const unsigned short* Asrc = Ab + (long)(wave * 32 + (lane >> 3)) * 512 + perm;
  const unsigned short* Bsrc = Bb + (long)(wave * 32 + (lane >> 3)) * 512 + perm;
  char* Adst = As + wave * 32 * 128;
  char* Bdst = Bs + wave * 32 * 128;

  for (int kt = 0; kt < 8; ++kt) {
    __syncthreads();
#pragma unroll
    for (int i = 0; i < 4; ++i) {
      gload_lds16(Asrc + (long)i * 8 * 512 + kt * 64, Adst + i * 1024);
      gload_lds16(Bsrc + (long)i * 8 * 512 + kt * 64, Bdst + i * 1024);
    }
    __syncthreads();
#pragma unroll
    for (int ks = 0; ks < 2; ++ks) {
      bf16x8_t af[4], bfv[4];
#pragma unroll
      for (int mi = 0; mi < 4; ++mi) {
        int r = wr * 64 + mi * 16 + lrow;
        int o = r * 128 + ks * 64 + kgrp * 16;
        o ^= (r & 7) << 4;
        af[mi] = *(bf16x8_t*)(As + o);
      }
#pragma unroll
      for (int ni = 0; ni < 4; ++ni) {
        int r = wc * 64 + ni * 16 + lrow;
        int o = r * 128 + ks * 64 + kgrp * 16;
        o ^= (r & 7) << 4;
        bfv[ni] = *(bf16x8_t*)(Bs + o);
      }
#pragma unroll
      for (int mi = 0; mi < 4; ++mi)
#pragma unroll
        for (int ni = 0; ni < 4; ++ni)
          acc[mi][ni] = mfma16(af[mi], bfv[ni], acc[mi][ni]);
    }
  }

  int slab = blockIdx.x >> 2;
  const float* bias = slab == 0 ? qb : (slab == 1 ? kb : vb);
  float scl = slab == 0 ? scale : 1.f;
  int rowloc = (blockIdx.x & 3) * 128 + wr * 64;  // c within slab
  int colbase = blockIdx.y * 128 + wc * 64;       // n
  unsigned short* ob =
      (slab == 0 ? Q2 : (slab == 1 ? K2 : V2)) + ((long)bz << 19);
#pragma unroll
  for (int mi = 0; mi < 4; ++mi) {
#pragma unroll
    for (int ni = 0; ni < 4; ++ni) {
      int row0 = rowloc + mi * 16 + kgrp * 4;
      int col = colbase + ni * 16 + lrow;
      unsigned short us[4];
#pragma unroll
      for (int rg = 0; rg < 4; ++rg)
        us[rg] = f2bf((acc[mi][ni][rg] + bias[row0 + rg]) * scl);
      if (slab < 2) {
        long off = ((long)(col >> 4) << 13) + ((long)(row0 >> 3) << 7) +
                   ((col & 15) << 3) + (row0 & 7);
        *(ushort4*)(ob + off) = make_ushort4(us[0], us[1], us[2], us[3]);
      } else {
        long base16 = ((long)(row0 >> 4) << 14) + ((long)(col >> 3) << 7) +
                      (col & 7) + (row0 & 15) * 8;
#pragma unroll
        for (int rg = 0; rg < 4; ++rg) ob[base16 + rg * 8] = us[rg];
      }
    }
  }
}

// ---------------------------------------------------------------- fused attn+PV
// 512 blocks (b = f&15 pins batch to XCD b%8; 2 blocks/CU). Per block: 32 q-rows.
// Phase 1: QK^T from frag-blocked Q2/K2 (contiguous 1KB wave loads), exact
// softmax over all 1024 keys (scores never leave registers).
// Phase 2: P (unnormalized exp, <=1) staged to LDS frag-blocked w/ chunk-XOR;
// each wave then computes a 128-channel O slice over all j, V from V2 (L2),
// scaled by 1/sum in the epilogue. Output AO (b,n,c) bf16.
__global__ __launch_bounds__(256, 2) void attn_pv_k(
    const unsigned short* __restrict__ q2, const unsigned short* __restrict__ k2,
    const unsigned short* __restrict__ v2, unsigned short* __restrict__ ao) {
  int f = blockIdx.x;
  int b = f & 15, ib = f >> 4;  // rows ib*32..+32
  int tid = threadIdx.x, lane = tid & 63, wave = tid >> 6;
  int lrow = lane & 15, kgrp = lane >> 4;
  __shared__ unsigned short P2[32768];  // [2][j/8=128][16x8 frag] = 64KB
  __shared__ float red[2][4][32];
  f32x4_t acc[2][16];
#pragma unroll
  for (int h = 0; h < 2; ++h)
#pragma unroll
    for (int t = 0; t < 16; ++t) acc[h][t] = (f32x4_t){0.f, 0.f, 0.f, 0.f};
  const unsigned short* qb =
      q2 + ((long)b << 19) + ((long)(ib * 2) << 13) + lane * 8;
  const unsigned short* kb =
      k2 + ((long)b << 19) + ((long)(wave * 16) << 13) + lane * 8;
  for (int ks = 0; ks < 16; ++ks) {  // K = 512
    bf16x8_t qa[2];
    qa[0] = *(const bf16x8_t*)(qb + ks * 512);
    qa[1] = *(const bf16x8_t*)(qb + 8192 + ks * 512);
    bf16x8_t kf[16];
#pragma unroll
    for (int t = 0; t < 16; ++t)
      kf[t] = *(const bf16x8_t*)(kb + t * 8192 + ks * 512);
#pragma unroll
    for (int t = 0; t < 16; ++t) {
      acc[0][t] = mfma16(qa[0], kf[t], acc[0][t]);
      acc[1][t] = mfma16(qa[1], kf[t], acc[1][t]);
    }
  }
  // ---- softmax (rows r = h*16 + kgrp*4 + rg; cols split across waves) ----
  float mx[2][4] = {{-1e30f, -1e30f, -1e30f, -1e30f},
                    {-1e30f, -1e30f, -1e30f, -1e30f}};
#pragma unroll
  for (int h = 0; h < 2; ++h)
#pragma unroll
    for (int t = 0; t < 16; ++t)
#pragma unroll
      for (int rg = 0; rg < 4; ++rg) mx[h][rg] = fmaxf(mx[h][rg], acc[h][t][rg]);
#pragma unroll
  for (int m = 1; m < 16; m <<= 1)
#pragma unroll
    for (int h = 0; h < 2; ++h)
#pragma unroll
      for (int rg = 0; rg < 4; ++rg)
        mx[h][rg] = fmaxf(mx[h][rg], __shfl_xor(mx[h][rg], m));
  if (lrow == 0) {
#pragma unroll
    for (int h = 0; h < 2; ++h)
#pragma unroll
      for (int rg = 0; rg < 4; ++rg)
        red[0][wave][h * 16 + kgrp * 4 + rg] = mx[h][rg];
  }
  __syncthreads();
  float gm[2][4], sm[2][4] = {{0.f, 0.f, 0.f, 0.f}, {0.f, 0.f, 0.f, 0.f}};
#pragma unroll
  for (int h = 0; h < 2; ++h)
#pragma unroll
    for (int rg = 0; rg < 4; ++rg) {
      int r = h * 16 + kgrp * 4 + rg;
      gm[h][rg] = fmaxf(fmaxf(red[0][0][r], red[0][1][r]),
                        fmaxf(red[0][2][r], red[0][3][r]));
    }
  // exp + stage P to LDS: elem off = h*16384 + jb*128 + chunk^ (jb&7) swizzle
#pragma unroll
  for (int h = 0; h < 2; ++h)
#pragma unroll
    for (int t = 0; t < 16; ++t) {
      int j = wave * 256 + t * 16 + lrow;
      int jb = j >> 3;
      int ob = h * 16384 + jb * 128 + (j & 7);
      int cx = (jb & 7) << 3;
#pragma unroll
      for (int rg = 0; rg < 4; ++rg) {
        float p = __expf(acc[h][t][rg] - gm[h][rg]);
        sm[h][rg] += p;
        P2[ob + (((kgrp * 4 + rg) << 3) ^ cx)] = f2bf(p);
      }
    }
#pragma unroll
  for (int m = 1; m < 16; m <<= 1)
#pragma unroll
    for (int h = 0; h < 2; ++h)
#pragma unroll
      for (int rg = 0; rg < 4; ++rg) sm[h][rg] += __shfl_xor(sm[h][rg], m);
  if (lrow == 0) {
#pragma unroll
    for (int h = 0; h < 2; ++h)
#pragma unroll
      for (int rg = 0; rg < 4; ++rg)
        red[1][wave][h * 16 + kgrp * 4 + rg] = sm[h][rg];
  }
  __syncthreads();
  float inv[2][4];
#pragma unroll
  for (int h = 0; h < 2; ++h)
#pragma unroll
    for (int rg = 0; rg < 4; ++rg) {
      int r = h * 16 + kgrp * 4 + rg;
      inv[h][rg] =
          1.f / (red[1][0][r] + red[1][1][r] + red[1][2][r] + red[1][3][r]);
    }
  // ---- PV: wave owns channels [wave*128, +128), j = all 1024 ----
  f32x4_t o[2][8];
#pragma unroll
  for (int h = 0; h < 2; ++h)
#pragma unroll
    for (int cf = 0; cf < 8; ++cf) o[h][cf] = (f32x4_t){0.f, 0.f, 0.f, 0.f};
  const unsigned short* vbp =
      v2 + ((long)b << 19) + ((long)(wave * 8) << 14) + lane * 8;
  for (int js = 0; js < 32; ++js) {
    int jb = js * 4 + kgrp;
    int po = jb * 128 + ((lrow ^ (jb & 7)) << 3);
    bf16x8_t pa[2];
    pa[0] = *(const bf16x8_t*)&P2[po];
    pa[1] = *(const bf16x8_t*)&P2[16384 + po];
    bf16x8_t vf[8];
#pragma unroll
    for (int cf = 0; cf < 8; ++cf)
      vf[cf] = *(const bf16x8_t*)(vbp + cf * 16384 + js * 512);
#pragma unroll
    for (int cf = 0; cf < 8; ++cf) {
      o[0][cf] = mfma16(pa[0], vf[cf], o[0][cf]);
      o[1][cf] = mfma16(pa[1], vf[cf], o[1][cf]);
    }
  }
  unsigned short* aob = ao + ((long)(b * N_ + ib * 32)) * C_;
#pragma unroll
  for (int h = 0; h < 2; ++h)
#pragma unroll
    for (int cf = 0; cf < 8; ++cf) {
      int c = wave * 128 + cf * 16 + lrow;
#pragma unroll
      for (int rg = 0; rg < 4; ++rg) {
        int i = h * 16 + kgrp * 4 + rg;
        aob[(long)i * C_ + c] = f2bf(o[h][cf][rg] * inv[h][rg]);
      }
    }
}

// ---------------------------------------------------------------- proj GEMM
// out = x + Wp*AO^T + pb (fp32, (b,c,n)); A=Wp (512x512), B=AO (b,n,c).
__global__ __launch_bounds__(256) void gemm_proj(
    const unsigned short* __restrict__ A, const unsigned short* __restrict__ Bm,
    const float* __restrict__ bias, const float* __restrict__ resid,
    float* __restrict__ outp) {
  int bz = blockIdx.z;
  const unsigned short* Ab = A + (long)blockIdx.x * 128 * 512;
  const unsigned short* Bb =
      Bm + (long)bz * N_ * C_ + (long)blockIdx.y * 128 * 512;
  __shared__ char lds[32768];
  char* As = lds;
  char* Bs = lds + 16384;
  int tid = threadIdx.x;
  int lane = tid & 63, wave = tid >> 6;
  int wr = wave >> 1, wc = wave & 1;
  int lrow = lane & 15, kgrp = lane >> 4;
  f32x4_t acc[4][4];
#pragma unroll
  for (int i = 0; i < 4; ++i)
#pragma unroll
    for (int j = 0; j < 4; ++j) acc[i][j] = (f32x4_t){0.f, 0.f, 0.f, 0.f};

  int perm = (((lane & 7) ^ (lane >> 3)) << 3);
  const unsigned short* Asrc = Ab + (long)(wave * 32 + (lane >> 3)) * 512 + perm;
  const unsigned short* Bsrc = Bb + (long)(wave * 32 + (lane >> 3)) * 512 + perm;
  char* Adst = As + wave * 32 * 128;
  char* Bdst = Bs + wave * 32 * 128;

  for (int kt = 0; kt < 8; ++kt) {
    __syncthreads();
#pragma unroll
    for (int i = 0; i < 4; ++i) {
      gload_lds16(Asrc + (long)i * 8 * 512 + kt * 64, Adst + i * 1024);
      gload_lds16(Bsrc + (long)i * 8 * 512 + kt * 64, Bdst + i * 1024);
    }
    __syncthreads();
#pragma unroll
    for (int ks = 0; ks < 2; ++ks) {
      bf16x8_t af[4], bfv[4];
#pragma unroll
      for (int mi = 0; mi < 4; ++mi) {
        int r = wr * 64 + mi * 16 + lrow;
        int o = r * 128 + ks * 64 + kgrp * 16;
        o ^= (r & 7) << 4;
        af[mi] = *(bf16x8_t*)(As + o);
      }
#pragma unroll
      for (int ni = 0; ni < 4; ++ni) {
        int r = wc * 64 + ni * 16 + lrow;
        int o = r * 128 + ks * 64 + kgrp * 16;
        o ^= (r & 7) << 4;
        bfv[ni] = *(bf16x8_t*)(Bs + o);
      }
#pragma unroll
      for (int mi = 0; mi < 4; ++mi)
#pragma unroll
        for (int ni = 0; ni < 4; ++ni)
          acc[mi][ni] = mfma16(af[mi], bfv[ni], acc[mi][ni]);
    }
  }

  int rowbase = blockIdx.x * 128 + wr * 64;
  int colbase = blockIdx.y * 128 + wc * 64;
  float* ob = outp + (long)bz * C_ * N_;
  const float* rb = resid + (long)bz * C_ * N_;
#pragma unroll
  for (int mi = 0; mi < 4; ++mi) {
#pragma unroll
    for (int ni = 0; ni < 4; ++ni) {
      int row0 = rowbase + mi * 16 + kgrp * 4;
      int col = colbase + ni * 16 + lrow;
#pragma unroll
      for (int rg = 0; rg < 4; ++rg) {
        int r = row0 + rg;
        ob[(long)r * N_ + col] =
            acc[mi][ni][rg] + bias[r] + rb[(long)r * N_ + col];
      }
    }
  }
}

// ---------------------------------------------------------------- launch
extern "C" void kernel_launch(void* const* d_in, const int* in_sizes, int n_in,
                              void* d_out, int out_size, void* d_ws,
                              size_t ws_size, hipStream_t stream) {
  (void)in_sizes; (void)n_in; (void)out_size; (void)ws_size;
  const float* x = (const float*)d_in[0];
  const float* nw = (const float*)d_in[1];
  const float* nb = (const float*)d_in[2];
  const float* qw = (const float*)d_in[3];
  const float* qbias = (const float*)d_in[4];
  const float* kw = (const float*)d_in[5];
  const float* kbias = (const float*)d_in[6];
  const float* vw = (const float*)d_in[7];
  const float* vbias = (const float*)d_in[8];
  const float* pw = (const float*)d_in[9];
  const float* pbias = (const float*)d_in[10];
  float* out = (float*)d_out;

  char* ws = (char*)d_ws;
  unsigned short* WQKV = (unsigned short*)(ws + 0);        // 3MB stacked
  unsigned short* Wp = (unsigned short*)(ws + 1572864);    // 0.5MB
  unsigned short* HN = (unsigned short*)(ws + 2097152);    // 16MB (b,n,c)
  unsigned short* Q2 = (unsigned short*)(ws + 18874368);   // 16MB frag [n/16][c/8]
  unsigned short* K2 = (unsigned short*)(ws + 35651584);   // 16MB frag [n/16][c/8]
  unsigned short* V2 = (unsigned short*)(ws + 52428800);   // 16MB frag [c/16][n/8]
  unsigned short* AO = (unsigned short*)(ws + 69206016);   // 16MB (b,n,c)
  float2* MV = (float2*)(ws + 102760448);                  // 4KB (b,g) stats

  castw_k<<<1024, 256, 0, stream>>>(qw, kw, vw, pw, WQKV, Wp);
  gnstats_k<<<512, 256, 0, stream>>>(x, MV);
  gnnorm_k<<<1024, 256, 0, stream>>>(x, nw, nb, MV, HN);

  const float scale = 0.04419417382415922f;  // 512^-0.5
  // q,k,v in one dispatch
  gemm_qkv<<<dim3(12, 8, B_), 256, 0, stream>>>(WQKV, HN, qbias, kbias, vbias,
                                                Q2, K2, V2, scale);
  // fused QK^T + softmax + PV -> AO (b,n,c)
  attn_pv_k<<<512, 256, 0, stream>>>(Q2, K2, V2, AO);
  // out = x + Wp*AO^T + pb (fp32, (b,c,n))
  gemm_proj<<<dim3(4, 8, B_), 256, 0, stream>>>(Wp, AO, pbias, x, out);
}

// Round 7
// 130.816 us; speedup vs baseline: 2.5707x; 1.1097x over previous
//
#include <hip/hip_runtime.h>

#define B_ 16
#define C_ 512
#define N_ 1024

typedef __attribute__((ext_vector_type(8))) short bf16x8_t;
typedef __attribute__((ext_vector_type(4))) float f32x4_t;

__device__ __forceinline__ unsigned short f2bf(float f) {
  unsigned int u = __float_as_uint(f);
  u += 0x7fffu + ((u >> 16) & 1u);
  return (unsigned short)(u >> 16);
}

__device__ __forceinline__ f32x4_t mfma16(bf16x8_t a, bf16x8_t b, f32x4_t c) {
  return __builtin_amdgcn_mfma_f32_16x16x32_bf16(a, b, c, 0, 0, 0);
}

// async global->LDS, 16B per lane; dest must be wave-uniform base (lane*16 added by HW)
__device__ __forceinline__ void gload_lds16(const void* g, void* l) {
  __builtin_amdgcn_global_load_lds(
      (const __attribute__((address_space(1))) unsigned int*)g,
      (__attribute__((address_space(3))) unsigned int*)l, 16, 0, 0);
}

// ---------------------------------------------------------------- weights cast
// Stacks Wq|Wk|Wv into one (1536x512) bf16 buffer for the fused qkv GEMM.
__global__ __launch_bounds__(256) void castw_k(
    const float* __restrict__ qw, const float* __restrict__ kw,
    const float* __restrict__ vw, const float* __restrict__ pw,
    unsigned short* __restrict__ Wqkv, unsigned short* __restrict__ Wp) {
  int i = blockIdx.x * 256 + threadIdx.x;  // 262144 elements each
  Wqkv[i] = f2bf(qw[i]);
  Wqkv[262144 + i] = f2bf(kw[i]);
  Wqkv[524288 + i] = f2bf(vw[i]);
  Wp[i] = f2bf(pw[i]);
}

// ---------------------------------------------------------------- GN stats
__global__ __launch_bounds__(256) void gnstats_k(
    const float* __restrict__ x, float2* __restrict__ mv) {
  int b = blockIdx.x >> 5, g = blockIdx.x & 31;
  int t = threadIdx.x;
  const float* xg = x + ((long)b * C_ + g * 16) * N_;
  float s = 0.f, s2 = 0.f;
  for (int i = t; i < 4096; i += 256) {
    float4 v = ((const float4*)xg)[i];
    s += v.x + v.y + v.z + v.w;
    s2 += v.x * v.x + v.y * v.y + v.z * v.z + v.w * v.w;
  }
#pragma unroll
  for (int m = 1; m < 64; m <<= 1) {
    s += __shfl_xor(s, m);
    s2 += __shfl_xor(s2, m);
  }
  __shared__ float rs[4], rs2[4];
  int wave = t >> 6;
  if ((t & 63) == 0) { rs[wave] = s; rs2[wave] = s2; }
  __syncthreads();
  if (t == 0) {
    s = rs[0] + rs[1] + rs[2] + rs[3];
    s2 = rs2[0] + rs2[1] + rs2[2] + rs2[3];
    float mean = s * (1.f / 16384.f);
    float rv = rsqrtf(s2 * (1.f / 16384.f) - mean * mean + 1e-5f);
    mv[b * 32 + g] = make_float2(mean, rv);
  }
}

// ---------------------------------------------------------------- GN normalize
// Full-64B-line transposed stores (no partial-line RMW).
__global__ __launch_bounds__(256) void gnnorm_k(
    const float* __restrict__ x, const float* __restrict__ gw,
    const float* __restrict__ gb, const float2* __restrict__ mv,
    unsigned short* __restrict__ hn) {
  int f = blockIdx.x;
  int b = f >> 6, gp = (f >> 2) & 15, nc = f & 3;
  int t = threadIdx.x;
  int quad = t & 3, nrow = t >> 2;
  int h2 = quad >> 1;
  float2 m = mv[b * 32 + gp * 2 + h2];
  int c0 = quad * 8;
  float ga[8], be[8];
#pragma unroll
  for (int jj = 0; jj < 8; ++jj) {
    int gc = gp * 32 + c0 + jj;
    ga[jj] = gw[gc] * m.y;
    be[jj] = gb[gc] - m.x * ga[jj];
  }
  const float* xg = x + ((long)b * C_ + gp * 32) * N_;
  unsigned short* ob = hn + (long)b * N_ * C_ + gp * 32 + c0;
  for (int j = 0; j < 4; ++j) {
    int n = nc * 256 + j * 64 + nrow;
    unsigned short us[8];
#pragma unroll
    for (int jj = 0; jj < 8; ++jj)
      us[jj] = f2bf(xg[(long)(c0 + jj) * N_ + n] * ga[jj] + be[jj]);
    *(uint4*)(ob + (long)n * C_) = *(uint4*)us;
  }
}

// ---------------------------------------------------------------- QKV GEMM
// A = stacked Wqkv (1536x512), B = HN (b,n,c). 128x128 tile, BK=64, gload_lds
// staging with source-side XOR permute. Epilogue per 512-row slab:
//  slab 0 -> Q2 frag-blocked [n/16][c/8][n%16][c%8], *scale
//  slab 1 -> K2 same layout
//  slab 2 -> V2 frag-blocked [c/16][n/8][c%16][n%8] (transposed roles for PV)
__global__ __launch_bounds__(256) void gemm_qkv(
    const unsigned short* __restrict__ W, const unsigned short* __restrict__ HN,
    const float* __restrict__ qb, const float* __restrict__ kb,
    const float* __restrict__ vb, unsigned short* __restrict__ Q2,
    unsigned short* __restrict__ K2, unsigned short* __restrict__ V2,
    float scale) {
  int bz = blockIdx.z;
  const unsigned short* Ab = W + (long)blockIdx.x * 128 * 512;
  const unsigned short* Bb =
      HN + (long)bz * N_ * C_ + (long)blockIdx.y * 128 * 512;
  __shared__ char lds[32768];
  char* As = lds;
  char* Bs = lds + 16384;
  int tid = threadIdx.x;
  int lane = tid & 63, wave = tid >> 6;
  int wr = wave >> 1, wc = wave & 1;
  int lrow = lane & 15, kgrp = lane >> 4;
  f32x4_t acc[4][4];
#pragma unroll
  for (int i = 0; i < 4; ++i)
#pragma unroll
    for (int j = 0; j < 4; ++j) acc[i][j] = (f32x4_t){0.f, 0.f, 0.f, 0.f};

  int perm = (((lane & 7) ^ (lane >> 3)) << 3);
  const unsigned short* Asrc = Ab + (long)(wave * 32 + (lane >> 3)) * 512 + perm;
  const unsigned short* Bsrc = Bb + (long)(wave * 32 + (lane >> 3)) * 512 + perm;
  char* Adst = As + wave * 32 * 128;
  char* Bdst = Bs + wave * 32 * 128;

  for (int kt = 0; kt < 8; ++kt) {
    __syncthreads();
#pragma unroll
    for (int i = 0; i < 4; ++i) {
      gload_lds16(Asrc + (long)i * 8 * 512 + kt * 64, Adst + i * 1024);
      gload_lds16(Bsrc + (long)i * 8 * 512 + kt * 64, Bdst + i * 1024);
    }
    __syncthreads();
#pragma unroll
    for (int ks = 0; ks < 2; ++ks) {
      bf16x8_t af[4], bfv[4];
#pragma unroll
      for (int mi = 0; mi < 4; ++mi) {
        int r = wr * 64 + mi * 16 + lrow;
        int o = r * 128 + ks * 64 + kgrp * 16;
        o ^= (r & 7) << 4;
        af[mi] = *(bf16x8_t*)(As + o);
      }
#pragma unroll
      for (int ni = 0; ni < 4; ++ni) {
        int r = wc * 64 + ni * 16 + lrow;
        int o = r * 128 + ks * 64 + kgrp * 16;
        o ^= (r & 7) << 4;
        bfv[ni] = *(bf16x8_t*)(Bs + o);
      }
#pragma unroll
      for (int mi = 0; mi < 4; ++mi)
#pragma unroll
        for (int ni = 0; ni < 4; ++ni)
          acc[mi][ni] = mfma16(af[mi], bfv[ni], acc[mi][ni]);
    }
  }

  int slab = blockIdx.x >> 2;
  const float* bias = slab == 0 ? qb : (slab == 1 ? kb : vb);
  float scl = slab == 0 ? scale : 1.f;
  int rowloc = (blockIdx.x & 3) * 128 + wr * 64;  // c within slab
  int colbase = blockIdx.y * 128 + wc * 64;       // n
  unsigned short* ob =
      (slab == 0 ? Q2 : (slab == 1 ? K2 : V2)) + ((long)bz << 19);
#pragma unroll
  for (int mi = 0; mi < 4; ++mi) {
#pragma unroll
    for (int ni = 0; ni < 4; ++ni) {
      int row0 = rowloc + mi * 16 + kgrp * 4;
      int col = colbase + ni * 16 + lrow;
      unsigned short us[4];
#pragma unroll
      for (int rg = 0; rg < 4; ++rg)
        us[rg] = f2bf((acc[mi][ni][rg] + bias[row0 + rg]) * scl);
      if (slab < 2) {
        long off = ((long)(col >> 4) << 13) + ((long)(row0 >> 3) << 7) +
                   ((col & 15) << 3) + (row0 & 7);
        *(ushort4*)(ob + off) = make_ushort4(us[0], us[1], us[2], us[3]);
      } else {
        long base16 = ((long)(row0 >> 4) << 14) + ((long)(col >> 3) << 7) +
                      (col & 7) + (row0 & 15) * 8;
#pragma unroll
        for (int rg = 0; rg < 4; ++rg) ob[base16 + rg * 8] = us[rg];
      }
    }
  }
}

// ---------------------------------------------------------------- fused attn+PV
// 256 blocks x 512 threads (8 waves); b = f&15 pins batch to XCD b%8; exactly
// 1 block/CU. Per block: 64 q-rows. Phase 1: QK^T, wave owns 128 key cols;
// exact softmax (8-wave LDS reduce). Phase 2: P (64x1024 bf16 = 128KB) staged
// frag-blocked in LDS with chunk-XOR; wave computes a 64-channel O slice over
// all 1024 j from frag-blocked V2 (L2-resident). Halves per-batch K2/V2 L2
// re-reads vs 32-row blocks.
__global__ __launch_bounds__(512, 1) void attn_pv_k(
    const unsigned short* __restrict__ q2, const unsigned short* __restrict__ k2,
    const unsigned short* __restrict__ v2, unsigned short* __restrict__ ao) {
  int f = blockIdx.x;
  int b = f & 15, ib = f >> 4;  // rows ib*64..+64
  int tid = threadIdx.x, lane = tid & 63, wave = tid >> 6;  // 8 waves
  int lrow = lane & 15, kgrp = lane >> 4;
  __shared__ unsigned short P2[65536];  // [4 h][128 jb][16x8 frag] = 128KB
  __shared__ float red[2][8][64];
  f32x4_t acc[4][8];
#pragma unroll
  for (int h = 0; h < 4; ++h)
#pragma unroll
    for (int t = 0; t < 8; ++t) acc[h][t] = (f32x4_t){0.f, 0.f, 0.f, 0.f};
  const unsigned short* qb =
      q2 + ((long)b << 19) + ((long)(ib * 4) << 13) + lane * 8;
  const unsigned short* kb =
      k2 + ((long)b << 19) + ((long)(wave * 8) << 13) + lane * 8;
  for (int ks = 0; ks < 16; ++ks) {  // K = 512
    bf16x8_t qa[4];
#pragma unroll
    for (int h = 0; h < 4; ++h)
      qa[h] = *(const bf16x8_t*)(qb + h * 8192 + ks * 512);
    bf16x8_t kf[8];
#pragma unroll
    for (int t = 0; t < 8; ++t)
      kf[t] = *(const bf16x8_t*)(kb + t * 8192 + ks * 512);
#pragma unroll
    for (int h = 0; h < 4; ++h)
#pragma unroll
      for (int t = 0; t < 8; ++t) acc[h][t] = mfma16(qa[h], kf[t], acc[h][t]);
  }
  // ---- softmax (rows r = h*16 + kgrp*4 + rg; cols split across 8 waves) ----
  float mx[4][4];
#pragma unroll
  for (int h = 0; h < 4; ++h)
#pragma unroll
    for (int rg = 0; rg < 4; ++rg) mx[h][rg] = -1e30f;
#pragma unroll
  for (int h = 0; h < 4; ++h)
#pragma unroll
    for (int t = 0; t < 8; ++t)
#pragma unroll
      for (int rg = 0; rg < 4; ++rg) mx[h][rg] = fmaxf(mx[h][rg], acc[h][t][rg]);
#pragma unroll
  for (int m = 1; m < 16; m <<= 1)
#pragma unroll
    for (int h = 0; h < 4; ++h)
#pragma unroll
      for (int rg = 0; rg < 4; ++rg)
        mx[h][rg] = fmaxf(mx[h][rg], __shfl_xor(mx[h][rg], m));
  if (lrow == 0) {
#pragma unroll
    for (int h = 0; h < 4; ++h)
#pragma unroll
      for (int rg = 0; rg < 4; ++rg)
        red[0][wave][h * 16 + kgrp * 4 + rg] = mx[h][rg];
  }
  __syncthreads();
  float gm[4][4], sm[4][4];
#pragma unroll
  for (int h = 0; h < 4; ++h)
#pragma unroll
    for (int rg = 0; rg < 4; ++rg) {
      int r = h * 16 + kgrp * 4 + rg;
      float g0 = fmaxf(fmaxf(red[0][0][r], red[0][1][r]),
                       fmaxf(red[0][2][r], red[0][3][r]));
      float g1 = fmaxf(fmaxf(red[0][4][r], red[0][5][r]),
                       fmaxf(red[0][6][r], red[0][7][r]));
      gm[h][rg] = fmaxf(g0, g1);
      sm[h][rg] = 0.f;
    }
  // exp + stage P to LDS: off = h*16384 + jb*128 + (j&7) + ((row<<3)^cx)
#pragma unroll
  for (int h = 0; h < 4; ++h)
#pragma unroll
    for (int t = 0; t < 8; ++t) {
      int j = wave * 128 + t * 16 + lrow;
      int jb = j >> 3;
      int ob = h * 16384 + jb * 128 + (j & 7);
      int cx = (jb & 7) << 3;
#pragma unroll
      for (int rg = 0; rg < 4; ++rg) {
        float p = __expf(acc[h][t][rg] - gm[h][rg]);
        sm[h][rg] += p;
        P2[ob + (((kgrp * 4 + rg) << 3) ^ cx)] = f2bf(p);
      }
    }
#pragma unroll
  for (int m = 1; m < 16; m <<= 1)
#pragma unroll
    for (int h = 0; h < 4; ++h)
#pragma unroll
      for (int rg = 0; rg < 4; ++rg) sm[h][rg] += __shfl_xor(sm[h][rg], m);
  if (lrow == 0) {
#pragma unroll
    for (int h = 0; h < 4; ++h)
#pragma unroll
      for (int rg = 0; rg < 4; ++rg)
        red[1][wave][h * 16 + kgrp * 4 + rg] = sm[h][rg];
  }
  __syncthreads();
  float inv[4][4];
#pragma unroll
  for (int h = 0; h < 4; ++h)
#pragma unroll
    for (int rg = 0; rg < 4; ++rg) {
      int r = h * 16 + kgrp * 4 + rg;
      float s0 = red[1][0][r] + red[1][1][r] + red[1][2][r] + red[1][3][r];
      float s1 = red[1][4][r] + red[1][5][r] + red[1][6][r] + red[1][7][r];
      inv[h][rg] = 1.f / (s0 + s1);
    }
  // ---- PV: wave owns channels [wave*64, +64), j = all 1024 ----
  f32x4_t o[4][4];
#pragma unroll
  for (int h = 0; h < 4; ++h)
#pragma unroll
    for (int cf = 0; cf < 4; ++cf) o[h][cf] = (f32x4_t){0.f, 0.f, 0.f, 0.f};
  const unsigned short* vbp =
      v2 + ((long)b << 19) + ((long)(wave * 4) << 14) + lane * 8;
  for (int js = 0; js < 32; ++js) {
    int jb = js * 4 + kgrp;
    int pox = ((lrow ^ (jb & 7)) << 3) + jb * 128;
    bf16x8_t pa[4];
#pragma unroll
    for (int h = 0; h < 4; ++h)
      pa[h] = *(const bf16x8_t*)&P2[h * 16384 + pox];
    bf16x8_t vf[4];
#pragma unroll
    for (int cf = 0; cf < 4; ++cf)
      vf[cf] = *(const bf16x8_t*)(vbp + cf * 16384 + js * 512);
#pragma unroll
    for (int h = 0; h < 4; ++h)
#pragma unroll
      for (int cf = 0; cf < 4; ++cf)
        o[h][cf] = mfma16(pa[h], vf[cf], o[h][cf]);
  }
  unsigned short* aob = ao + ((long)(b * N_ + ib * 64)) * C_;
#pragma unroll
  for (int h = 0; h < 4; ++h)
#pragma unroll
    for (int cf = 0; cf < 4; ++cf) {
      int c = wave * 64 + cf * 16 + lrow;
#pragma unroll
      for (int rg = 0; rg < 4; ++rg) {
        int i = h * 16 + kgrp * 4 + rg;
        aob[(long)i * C_ + c] = f2bf(o[h][cf][rg] * inv[h][rg]);
      }
    }
}

// ---------------------------------------------------------------- proj GEMM
// out = x + Wp*AO^T + pb (fp32, (b,c,n)); A=Wp (512x512), B=AO (b,n,c).
__global__ __launch_bounds__(256) void gemm_proj(
    const unsigned short* __restrict__ A, const unsigned short* __restrict__ Bm,
    const float* __restrict__ bias, const float* __restrict__ resid,
    float* __restrict__ outp) {
  int bz = blockIdx.z;
  const unsigned short* Ab = A + (long)blockIdx.x * 128 * 512;
  const unsigned short* Bb =
      Bm + (long)bz * N_ * C_ + (long)blockIdx.y * 128 * 512;
  __shared__ char lds[32768];
  char* As = lds;
  char* Bs = lds + 16384;
  int tid = threadIdx.x;
  int lane = tid & 63, wave = tid >> 6;
  int wr = wave >> 1, wc = wave & 1;
  int lrow = lane & 15, kgrp = lane >> 4;
  f32x4_t acc[4][4];
#pragma unroll
  for (int i = 0; i < 4; ++i)
#pragma unroll
    for (int j = 0; j < 4; ++j) acc[i][j] = (f32x4_t){0.f, 0.f, 0.f, 0.f};

  int perm = (((lane & 7) ^ (lane >> 3)) << 3);
  const unsigned short* Asrc = Ab + (long)(wave * 32 + (lane >> 3)) * 512 + perm;
  const unsigned short* Bsrc = Bb + (long)(wave * 32 + (lane >> 3)) * 512 + perm;
  char* Adst = As + wave * 32 * 128;
  char* Bdst = Bs + wave * 32 * 128;

  for (int kt = 0; kt < 8; ++kt) {
    __syncthreads();
#pragma unroll
    for (int i = 0; i < 4; ++i) {
      gload_lds16(Asrc + (long)i * 8 * 512 + kt * 64, Adst + i * 1024);
      gload_lds16(Bsrc + (long)i * 8 * 512 + kt * 64, Bdst + i * 1024);
    }
    __syncthreads();
#pragma unroll
    for (int ks = 0; ks < 2; ++ks) {
      bf16x8_t af[4], bfv[4];
#pragma unroll
      for (int mi = 0; mi < 4; ++mi) {
        int r = wr * 64 + mi * 16 + lrow;
        int o = r * 128 + ks * 64 + kgrp * 16;
        o ^= (r & 7) << 4;
        af[mi] = *(bf16x8_t*)(As + o);
      }
#pragma unroll
      for (int ni = 0; ni < 4; ++ni) {
        int r = wc * 64 + ni * 16 + lrow;
        int o = r * 128 + ks * 64 + kgrp * 16;
        o ^= (r & 7) << 4;
        bfv[ni] = *(bf16x8_t*)(Bs + o);
      }
#pragma unroll
      for (int mi = 0; mi < 4; ++mi)
#pragma unroll
        for (int ni = 0; ni < 4; ++ni)
          acc[mi][ni] = mfma16(af[mi], bfv[ni], acc[mi][ni]);
    }
  }

  int rowbase = blockIdx.x * 128 + wr * 64;
  int colbase = blockIdx.y * 128 + wc * 64;
  float* ob = outp + (long)bz * C_ * N_;
  const float* rb = resid + (long)bz * C_ * N_;
#pragma unroll
  for (int mi = 0; mi < 4; ++mi) {
#pragma unroll
    for (int ni = 0; ni < 4; ++ni) {
      int row0 = rowbase + mi * 16 + kgrp * 4;
      int col = colbase + ni * 16 + lrow;
#pragma unroll
      for (int rg = 0; rg < 4; ++rg) {
        int r = row0 + rg;
        ob[(long)r * N_ + col] =
            acc[mi][ni][rg] + bias[r] + rb[(long)r * N_ + col];
      }
    }
  }
}

// ---------------------------------------------------------------- launch
extern "C" void kernel_launch(void* const* d_in, const int* in_sizes, int n_in,
                              void* d_out, int out_size, void* d_ws,
                              size_t ws_size, hipStream_t stream) {
  (void)in_sizes; (void)n_in; (void)out_size; (void)ws_size;
  const float* x = (const float*)d_in[0];
  const float* nw = (const float*)d_in[1];
  const float* nb = (const float*)d_in[2];
  const float* qw = (const float*)d_in[3];
  const float* qbias = (const float*)d_in[4];
  const float* kw = (const float*)d_in[5];
  const float* kbias = (const float*)d_in[6];
  const float* vw = (const float*)d_in[7];
  const float* vbias = (const float*)d_in[8];
  const float* pw = (const float*)d_in[9];
  const float* pbias = (const float*)d_in[10];
  float* out = (float*)d_out;

  char* ws = (char*)d_ws;
  unsigned short* WQKV = (unsigned short*)(ws + 0);        // 3MB stacked
  unsigned short* Wp = (unsigned short*)(ws + 1572864);    // 0.5MB
  unsigned short* HN = (unsigned short*)(ws + 2097152);    // 16MB (b,n,c)
  unsigned short* Q2 = (unsigned short*)(ws + 18874368);   // 16MB frag [n/16][c/8]
  unsigned short* K2 = (unsigned short*)(ws + 35651584);   // 16MB frag [n/16][c/8]
  unsigned short* V2 = (unsigned short*)(ws + 52428800);   // 16MB frag [c/16][n/8]
  unsigned short* AO = (unsigned short*)(ws + 69206016);   // 16MB (b,n,c)
  float2* MV = (float2*)(ws + 102760448);                  // 4KB (b,g) stats

  castw_k<<<1024, 256, 0, stream>>>(qw, kw, vw, pw, WQKV, Wp);
  gnstats_k<<<512, 256, 0, stream>>>(x, MV);
  gnnorm_k<<<1024, 256, 0, stream>>>(x, nw, nb, MV, HN);

  const float scale = 0.04419417382415922f;  // 512^-0.5
  // q,k,v in one dispatch
  gemm_qkv<<<dim3(12, 8, B_), 256, 0, stream>>>(WQKV, HN, qbias, kbias, vbias,
                                                Q2, K2, V2, scale);
  // fused QK^T + softmax + PV -> AO (b,n,c)
  attn_pv_k<<<256, 512, 0, stream>>>(Q2, K2, V2, AO);
  // out = x + Wp*AO^T + pb (fp32, (b,c,n))
  gemm_proj<<<dim3(4, 8, B_), 256, 0, stream>>>(Wp, AO, pbias, x, out);
}